// Round 8
// baseline (692.943 us; speedup 1.0000x reference)
//
#include <hip/hip_runtime.h>

#define NNODES 20000
#define MPAD   20096    // NNODES padded to multiple of 128
#define NEDGES 320000
#define FIN    512
#define HC1    512      // H1*HID
#define NHEAD  8
#define OUT2   49
#define NCOL2  392      // NHEAD*OUT2
#define NB2    784      // 2*NCOL2
#define NPAD2  896      // NB2 padded to multiple of 128
#define NCLU   64
#define NIDX   10000
#define NEG    0.2f

typedef unsigned short u16;
typedef short bf16x8 __attribute__((ext_vector_type(8)));
typedef float f32x4 __attribute__((ext_vector_type(4)));

static __device__ __forceinline__ float lrelu(float v){ return v > 0.f ? v : NEG*v; }

// exact split (truncation): f = hi + rem
static __device__ __forceinline__ u16 f2bf_hi(float f, float& rem) {
  union { float f; unsigned u; } c; c.f = f;
  unsigned hb = c.u & 0xFFFF0000u;
  union { unsigned u; float f; } d; d.u = hb;
  rem = f - d.f;
  return (u16)(hb >> 16);
}
static __device__ __forceinline__ u16 f2bf(float f) {   // truncate
  union { float f; unsigned u; } c; c.f = f;
  return (u16)(c.u >> 16);
}
static __device__ __forceinline__ u16 f2bf_rn(float f) { // round-nearest-even
  union { float f; unsigned u; } c; c.f = f;
  unsigned r = c.u + 0x7FFFu + ((c.u >> 16) & 1u);
  return (u16)(r >> 16);
}
static __device__ __forceinline__ float bf2f(u16 u) {
  union { unsigned u; float f; } c; c.u = ((unsigned)u) << 16;
  return c.f;
}
static __device__ __forceinline__ void load8bf(const u16* p, float* o) {
  ushort4 a = *(const ushort4*)p;
  ushort4 b = *(const ushort4*)(p + 4);
  o[0]=bf2f(a.x); o[1]=bf2f(a.y); o[2]=bf2f(a.z); o[3]=bf2f(a.w);
  o[4]=bf2f(b.x); o[5]=bf2f(b.y); o[6]=bf2f(b.z); o[7]=bf2f(b.w);
}

// async 16B global->LDS
typedef __attribute__((address_space(3))) unsigned int lds_u32;
typedef __attribute__((address_space(1))) const unsigned int glb_u32;
static __device__ __forceinline__ void gl_lds16(const u16* g, u16* l) {
  __builtin_amdgcn_global_load_lds((glb_u32*)g, (lds_u32*)l, 16, 0, 0);
}

// ---------------- split x -> packed [kc][row][8], coalesced both sides via LDS ----------------
__global__ __launch_bounds__(256) void split4_kernel(const float* __restrict__ x,
                                                     u16* __restrict__ xh, u16* __restrict__ xl) {
  __shared__ __align__(16) u16 th[4][512], tl[4][512];
  int wv = threadIdx.x >> 6;
  int lane = threadIdx.x & 63;
  int i = blockIdx.x*4 + wv;
  const float* p = x + (size_t)i*FIN + lane*8;
  float4 v0 = *(const float4*)p, v1 = *(const float4*)(p+4);
  float rem; ushort4 h0,h1,l0,l1;
  h0.x = f2bf_hi(v0.x, rem); l0.x = f2bf(rem);
  h0.y = f2bf_hi(v0.y, rem); l0.y = f2bf(rem);
  h0.z = f2bf_hi(v0.z, rem); l0.z = f2bf(rem);
  h0.w = f2bf_hi(v0.w, rem); l0.w = f2bf(rem);
  h1.x = f2bf_hi(v1.x, rem); l1.x = f2bf(rem);
  h1.y = f2bf_hi(v1.y, rem); l1.y = f2bf(rem);
  h1.z = f2bf_hi(v1.z, rem); l1.z = f2bf(rem);
  h1.w = f2bf_hi(v1.w, rem); l1.w = f2bf(rem);
  *(ushort4*)&th[wv][lane*8]   = h0; *(ushort4*)&th[wv][lane*8+4] = h1;
  *(ushort4*)&tl[wv][lane*8]   = l0; *(ushort4*)&tl[wv][lane*8+4] = l1;
  __syncthreads();
  int kc = threadIdx.x >> 2, nd = threadIdx.x & 3;
  size_t o = ((size_t)kc*MPAD + blockIdx.x*4 + nd)*8;
  *(uint4*)&xh[o] = *(const uint4*)&th[nd][kc*8];
  *(uint4*)&xl[o] = *(const uint4*)&tl[nd][kc*8];
}

__global__ void tw1_kernel(const float* __restrict__ W1, u16* __restrict__ Th, u16* __restrict__ Tl) {
  int tid = blockIdx.x*256 + threadIdx.x;   // < 64*512
  int kc = tid >> 9, j = tid & 511;
  float rem; ushort4 h0,h1,l0,l1;
  h0.x = f2bf_hi(W1[(size_t)(kc*8+0)*512 + j], rem); l0.x = f2bf(rem);
  h0.y = f2bf_hi(W1[(size_t)(kc*8+1)*512 + j], rem); l0.y = f2bf(rem);
  h0.z = f2bf_hi(W1[(size_t)(kc*8+2)*512 + j], rem); l0.z = f2bf(rem);
  h0.w = f2bf_hi(W1[(size_t)(kc*8+3)*512 + j], rem); l0.w = f2bf(rem);
  h1.x = f2bf_hi(W1[(size_t)(kc*8+4)*512 + j], rem); l1.x = f2bf(rem);
  h1.y = f2bf_hi(W1[(size_t)(kc*8+5)*512 + j], rem); l1.y = f2bf(rem);
  h1.z = f2bf_hi(W1[(size_t)(kc*8+6)*512 + j], rem); l1.z = f2bf(rem);
  h1.w = f2bf_hi(W1[(size_t)(kc*8+7)*512 + j], rem); l1.w = f2bf(rem);
  size_t o = ((size_t)kc*512 + j)*8;
  *(ushort4*)&Th[o] = h0; *(ushort4*)&Th[o+4] = h1;
  *(ushort4*)&Tl[o] = l0; *(ushort4*)&Tl[o+4] = l1;
}

__global__ void tb2_kernel(const float* __restrict__ W2, u16* __restrict__ Th, u16* __restrict__ Tl) {
  int tid = blockIdx.x*256 + threadIdx.x;   // < 64*896
  int kc = tid / NPAD2, j = tid - kc*NPAD2;
  float v[8];
  #pragma unroll
  for (int e = 0; e < 8; e++) {
    int k = kc*8 + e;
    v[e] = (j < NCOL2) ? W2[(size_t)k*NCOL2 + j]
         : ((j < NB2) ? W2[(size_t)(512+k)*NCOL2 + (j - NCOL2)] : 0.f);
  }
  float rem; ushort4 h0,h1,l0,l1;
  h0.x = f2bf_hi(v[0], rem); l0.x = f2bf(rem);
  h0.y = f2bf_hi(v[1], rem); l0.y = f2bf(rem);
  h0.z = f2bf_hi(v[2], rem); l0.z = f2bf(rem);
  h0.w = f2bf_hi(v[3], rem); l0.w = f2bf(rem);
  h1.x = f2bf_hi(v[4], rem); l1.x = f2bf(rem);
  h1.y = f2bf_hi(v[5], rem); l1.y = f2bf(rem);
  h1.z = f2bf_hi(v[6], rem); l1.z = f2bf(rem);
  h1.w = f2bf_hi(v[7], rem); l1.w = f2bf(rem);
  size_t o = ((size_t)kc*NPAD2 + j)*8;
  *(ushort4*)&Th[o] = h0; *(ushort4*)&Th[o+4] = h1;
  *(ushort4*)&Tl[o] = l0; *(ushort4*)&Tl[o+4] = l1;
}

// ---------------- split-bf16 MFMA GEMM: double-buffered async staging, 1 barrier/iter ----------------
// Streams per buffer (u16 idx): Ah@0, Al@4096, Bh@8192, Bl@12288; chunk plane stride 1024.
template<int EPI>
__global__ __launch_bounds__(256) void gemm_mfma(
    const u16* __restrict__ Ah, const u16* __restrict__ Al,
    const u16* __restrict__ Bh, const u16* __restrict__ Bl,
    int Apitch, int Bpitch,
    u16* __restrict__ Cbf, int M, int Ncols,
    const int* __restrict__ cmax, const float* __restrict__ CFW, u16* __restrict__ h2)
{
  __shared__ __align__(16) u16 S[2][16384];   // 64 KB total
  int tid = threadIdx.x;
  int lane = tid & 63;
  int w = tid >> 6;
  int row0 = blockIdx.x * 128;
  int col0 = blockIdx.y * 128;

  // wave w stages stream w
  const u16* G; size_t pitch;
  if      (w == 0) { G = Ah + ((size_t)row0 + lane)*8; pitch = (size_t)Apitch; }
  else if (w == 1) { G = Al + ((size_t)row0 + lane)*8; pitch = (size_t)Apitch; }
  else if (w == 2) { G = Bh + ((size_t)col0 + lane)*8; pitch = (size_t)Bpitch; }
  else             { G = Bl + ((size_t)col0 + lane)*8; pitch = (size_t)Bpitch; }
  int lb = w * 4096;

  int wr = (w >> 1) * 64;
  int wc = (w & 1) * 64;
  int l16 = lane & 15;
  int q = lane >> 4;

  f32x4 acc[4][4];
  #pragma unroll
  for (int i = 0; i < 4; i++)
    #pragma unroll
    for (int j = 0; j < 4; j++)
      acc[i][j] = (f32x4){0.f, 0.f, 0.f, 0.f};

  // prologue: issue tile 0 into S[0]
  #pragma unroll
  for (int c = 0; c < 4; c++) {
    const u16* g = G + ((size_t)c)*pitch*8;
    gl_lds16(g,       &S[0][lb + c*1024]);
    gl_lds16(g + 512, &S[0][lb + c*1024 + 512]);
  }

  for (int t = 0; t < 16; t++) {
    int cur = t & 1;
    __syncthreads();   // compiler-emitted vmcnt(0) drain: S[cur] loads done; prior reads of S[1-cur] done
    if (t < 15) {
      #pragma unroll
      for (int c = 0; c < 4; c++) {
        const u16* g = G + ((size_t)((t+1)*4 + c))*pitch*8;
        gl_lds16(g,       &S[1-cur][lb + c*1024]);
        gl_lds16(g + 512, &S[1-cur][lb + c*1024 + 512]);
      }
    }
    const u16* P = S[cur];
    bf16x8 ah[4], al[4], bh[4], bl[4];
    #pragma unroll
    for (int i = 0; i < 4; i++) {
      int ra = q*1024 + (wr + i*16 + l16)*8;
      int rb = q*1024 + (wc + i*16 + l16)*8;
      ah[i] = *(const bf16x8*)&P[ra];
      al[i] = *(const bf16x8*)&P[4096 + ra];
      bh[i] = *(const bf16x8*)&P[8192 + rb];
      bl[i] = *(const bf16x8*)&P[12288 + rb];
    }
    #pragma unroll
    for (int i = 0; i < 4; i++)
      #pragma unroll
      for (int j = 0; j < 4; j++)
        acc[i][j] = __builtin_amdgcn_mfma_f32_16x16x32_bf16(ah[i], bh[j], acc[i][j], 0, 0, 0);
    #pragma unroll
    for (int i = 0; i < 4; i++)
      #pragma unroll
      for (int j = 0; j < 4; j++)
        acc[i][j] = __builtin_amdgcn_mfma_f32_16x16x32_bf16(ah[i], bl[j], acc[i][j], 0, 0, 0);
    #pragma unroll
    for (int i = 0; i < 4; i++)
      #pragma unroll
      for (int j = 0; j < 4; j++)
        acc[i][j] = __builtin_amdgcn_mfma_f32_16x16x32_bf16(al[i], bh[j], acc[i][j], 0, 0, 0);
  }

  if (EPI == 0) {
    #pragma unroll
    for (int i = 0; i < 4; i++) {
      #pragma unroll
      for (int r = 0; r < 4; r++) {
        int m = row0 + wr + i*16 + q*4 + r;
        if (m < M) {
          #pragma unroll
          for (int j = 0; j < 4; j++)
            Cbf[(size_t)m*Ncols + col0 + wc + j*16 + l16] = f2bf_rn(acc[i][j][r]);
        }
      }
    }
  } else {
    #pragma unroll
    for (int i = 0; i < 4; i++) {
      #pragma unroll
      for (int r = 0; r < 4; r++) {
        int m = row0 + wr + i*16 + q*4 + r;
        if (m >= M) continue;
        int c = cmax[m];
        const float* cf = CFW + (size_t)c * NB2;
        #pragma unroll
        for (int j = 0; j < 4; j++) {
          int n = col0 + wc + j*16 + l16;
          if (n >= NB2) continue;
          float v = acc[i][j][r];
          if (n < NCOL2) h2[(size_t)m*NCOL2 + n] = f2bf_rn(v + cf[NCOL2 + n]);
          else           h2[(size_t)(NNODES + m)*NCOL2 + (n - NCOL2)] = f2bf_rn(v + cf[n - NCOL2]);
        }
      }
    }
  }
}

// ---------------- CSR build ----------------
__global__ void hist_kernel(const int* __restrict__ ei, int* __restrict__ counts) {
  int e = blockIdx.x*256 + threadIdx.x;
  if (e < NEDGES) atomicAdd(&counts[ei[NEDGES + e]], 1);
}

__global__ __launch_bounds__(1024) void scan_kernel(const int* __restrict__ counts,
                                                    int* __restrict__ rowptr, int* __restrict__ cursor) {
  __shared__ int part[1024];
  int t = threadIdx.x;
  const int CH = 20;
  int start = t*CH;
  int end = min(start+CH, NNODES);
  int sum = 0;
  for (int i = start; i < end; i++) sum += counts[i];
  part[t] = sum;
  __syncthreads();
  for (int off = 1; off < 1024; off <<= 1) {
    int v = part[t];
    int add = (t >= off) ? part[t-off] : 0;
    __syncthreads();
    part[t] = v + add;
    __syncthreads();
  }
  int run = part[t] - sum;
  for (int i = start; i < end; i++) {
    rowptr[i] = run; cursor[i] = run;
    run += counts[i];
  }
  if (t == 1023) rowptr[NNODES] = part[1023];
}

__global__ void scatter_kernel(const int* __restrict__ ei, int* __restrict__ cursor,
                               int* __restrict__ csr, int* __restrict__ dstid) {
  int e = blockIdx.x*256 + threadIdx.x;
  if (e < NEDGES) {
    int src = ei[e];
    int dst = ei[NEDGES + e];
    int pos = atomicAdd(&cursor[dst], 1);
    csr[pos] = src;
    dstid[pos] = dst;
  }
}

// ---------------- conv1 attention logits (bf16 hpre row-major) ----------------
__global__ __launch_bounds__(256) void a1_kernel(
    const u16* __restrict__ hpre, const float* __restrict__ atts, const float* __restrict__ attd,
    float* __restrict__ as1, float* __restrict__ ad1)
{
  int lane = threadIdx.x & 63;
  int i = blockIdx.x*4 + (threadIdx.x >> 6);
  float hv[8];
  load8bf(hpre + (size_t)i*HC1 + lane*8, hv);
  const float* ap = atts + lane*8; const float* dp = attd + lane*8;
  float ps = 0.f, pd = 0.f;
  #pragma unroll
  for (int k = 0; k < 8; k++) { ps = fmaf(hv[k], ap[k], ps); pd = fmaf(hv[k], dp[k], pd); }
  ps += __shfl_down(ps, 4, 8); ps += __shfl_down(ps, 2, 8); ps += __shfl_down(ps, 1, 8);
  pd += __shfl_down(pd, 4, 8); pd += __shfl_down(pd, 2, 8); pd += __shfl_down(pd, 1, 8);
  if ((lane & 7) == 0) {
    as1[i*8 + (lane >> 3)] = ps;
    ad1[i*8 + (lane >> 3)] = pd;
  }
}

// ---------------- edge-parallel exp kernels (denominator folded into agg) ----------------
__global__ void exp1_kernel(const int* __restrict__ csr, const int* __restrict__ dstid,
                            const float* __restrict__ as1, const float* __restrict__ ad1,
                            float* __restrict__ p1)
{
  int pos = blockIdx.x*256 + threadIdx.x;   // grid exact: E
  int src = csr[pos], dst = dstid[pos];
  const float* a = as1 + (size_t)src*8;
  const float* d = ad1 + (size_t)dst*8;
  float4 a0 = *(const float4*)a, a1v = *(const float4*)(a+4);
  float4 d0 = *(const float4*)d, d1v = *(const float4*)(d+4);
  float4 o0, o1;
  o0.x = __expf(lrelu(a0.x + d0.x));  o0.y = __expf(lrelu(a0.y + d0.y));
  o0.z = __expf(lrelu(a0.z + d0.z));  o0.w = __expf(lrelu(a0.w + d0.w));
  o1.x = __expf(lrelu(a1v.x + d1v.x)); o1.y = __expf(lrelu(a1v.y + d1v.y));
  o1.z = __expf(lrelu(a1v.z + d1v.z)); o1.w = __expf(lrelu(a1v.w + d1v.w));
  *(float4*)(p1 + (size_t)pos*8)     = o0;
  *(float4*)(p1 + (size_t)pos*8 + 4) = o1;
}

__global__ void exp2_kernel(const int* __restrict__ csr, const int* __restrict__ dstid,
                            const float* __restrict__ as2, const float* __restrict__ ad2,
                            float* __restrict__ p2)
{
  int pos2 = blockIdx.x*256 + threadIdx.x;  // grid exact: 2E
  int half = (pos2 >= NEDGES) ? 1 : 0;
  int pos = pos2 - half*NEDGES;
  int src = csr[pos] + half*NNODES;
  int dst = dstid[pos] + half*NNODES;
  const float* a = as2 + (size_t)src*8;
  const float* d = ad2 + (size_t)dst*8;
  float4 a0 = *(const float4*)a, a1v = *(const float4*)(a+4);
  float4 d0 = *(const float4*)d, d1v = *(const float4*)(d+4);
  float4 o0, o1;
  o0.x = __expf(lrelu(a0.x + d0.x));  o0.y = __expf(lrelu(a0.y + d0.y));
  o0.z = __expf(lrelu(a0.z + d0.z));  o0.w = __expf(lrelu(a0.w + d0.w));
  o1.x = __expf(lrelu(a1v.x + d1v.x)); o1.y = __expf(lrelu(a1v.y + d1v.y));
  o1.z = __expf(lrelu(a1v.z + d1v.z)); o1.w = __expf(lrelu(a1v.w + d1v.w));
  *(float4*)(p2 + (size_t)pos2*8)     = o0;
  *(float4*)(p2 + (size_t)pos2*8 + 4) = o1;
}

// ---------------- conv1 aggregation (s folded) + ELU -> row-major + packed split bf16 ----------------
__global__ __launch_bounds__(256) void agg1_kernel(
    const u16* __restrict__ hpre, const float* __restrict__ p1,
    const float* __restrict__ as1, const float* __restrict__ ad1,
    const int* __restrict__ rowptr, const int* __restrict__ csr, const float* __restrict__ b1,
    u16* __restrict__ hhr, u16* __restrict__ hlr,
    u16* __restrict__ hh, u16* __restrict__ hl)
{
  __shared__ __align__(16) u16 sh[4][512], sl[4][512];
  int lane = threadIdx.x & 63;
  int wv = threadIdx.x >> 6;
  int i = blockIdx.x*4 + wv;
  int hd = lane >> 3;
  int rs = rowptr[i];
  int deg = rowptr[i+1] - rs;
  float selfp = __expf(lrelu(as1[i*8 + hd] + ad1[i*8 + hd]));
  float acc[8];
  {
    float v[8];
    load8bf(hpre + (size_t)i*HC1 + lane*8, v);
    #pragma unroll
    for (int k = 0; k < 8; k++) acc[k] = selfp * v[k];
  }
  float s = selfp;
  int j = 0;
  for (; j + 1 < deg; j += 2) {
    int s0 = csr[rs+j], s1 = csr[rs+j+1];
    float w0 = p1[(size_t)(rs+j)*8 + hd];
    float w1 = p1[(size_t)(rs+j+1)*8 + hd];
    float v0[8], v1[8];
    load8bf(hpre + (size_t)s0*HC1 + lane*8, v0);
    load8bf(hpre + (size_t)s1*HC1 + lane*8, v1);
    #pragma unroll
    for (int k = 0; k < 8; k++) acc[k] = fmaf(w0, v0[k], acc[k]);
    #pragma unroll
    for (int k = 0; k < 8; k++) acc[k] = fmaf(w1, v1[k], acc[k]);
    s += w0 + w1;
  }
  if (j < deg) {
    int s0 = csr[rs+j];
    float w0 = p1[(size_t)(rs+j)*8 + hd];
    float v0[8];
    load8bf(hpre + (size_t)s0*HC1 + lane*8, v0);
    #pragma unroll
    for (int k = 0; k < 8; k++) acc[k] = fmaf(w0, v0[k], acc[k]);
    s += w0;
  }
  float inv = 1.f / s;
  float rem; ushort4 h0,h1,l0,l1;
  float o[8];
  #pragma unroll
  for (int k = 0; k < 8; k++) {
    float v = acc[k]*inv + b1[lane*8 + k];
    o[k] = v > 0.f ? v : __expf(v) - 1.f;   // ELU
  }
  h0.x = f2bf_hi(o[0], rem); l0.x = f2bf(rem);
  h0.y = f2bf_hi(o[1], rem); l0.y = f2bf(rem);
  h0.z = f2bf_hi(o[2], rem); l0.z = f2bf(rem);
  h0.w = f2bf_hi(o[3], rem); l0.w = f2bf(rem);
  h1.x = f2bf_hi(o[4], rem); l1.x = f2bf(rem);
  h1.y = f2bf_hi(o[5], rem); l1.y = f2bf(rem);
  h1.z = f2bf_hi(o[6], rem); l1.z = f2bf(rem);
  h1.w = f2bf_hi(o[7], rem); l1.w = f2bf(rem);
  size_t rb = (size_t)i*HC1 + lane*8;
  *(ushort4*)&hhr[rb]   = h0; *(ushort4*)&hhr[rb+4] = h1;
  *(ushort4*)&hlr[rb]   = l0; *(ushort4*)&hlr[rb+4] = l1;
  *(ushort4*)&sh[wv][lane*8]   = h0; *(ushort4*)&sh[wv][lane*8+4] = h1;
  *(ushort4*)&sl[wv][lane*8]   = l0; *(ushort4*)&sl[wv][lane*8+4] = l1;
  __syncthreads();
  int kc = threadIdx.x >> 2, nd = threadIdx.x & 3;
  size_t po = ((size_t)kc*MPAD + blockIdx.x*4 + nd)*8;
  *(uint4*)&hh[po] = *(const uint4*)&sh[nd][kc*8];
  *(uint4*)&hl[po] = *(const uint4*)&sl[nd][kc*8];
}

// ---------------- cluster stage ----------------
__global__ __launch_bounds__(256) void colsum_kernel(
    const float* __restrict__ cluster_id, const int* __restrict__ cidx, float* __restrict__ colsum)
{
  __shared__ float part[4][64];
  int tid = threadIdx.x; int q = tid >> 6, col = tid & 63;
  int start = blockIdx.x*313, end = min(start+313, NIDX);
  float acc = 0.f;
  for (int t = start + q; t < end; t += 4) {
    int node = cidx[t];
    acc += cluster_id[(size_t)node*NCLU + col];
  }
  part[q][col] = acc;
  __syncthreads();
  if (tid < 64) {
    float v = part[0][tid] + part[1][tid] + part[2][tid] + part[3][tid];
    atomicAdd(&colsum[tid], v);
  }
}

__global__ __launch_bounds__(256) void cf_kernel(
    const float* __restrict__ cluster_id, const int* __restrict__ cidx,
    const u16* __restrict__ hhr, const u16* __restrict__ hlr, float* __restrict__ CFraw)
{
  int chl = threadIdx.x & 63;
  int cq  = threadIdx.x >> 6;
  int chg = blockIdx.x*64 + chl;
  int start = blockIdx.y*400, end = start + 400;
  float acc[16];
  #pragma unroll
  for (int k = 0; k < 16; k++) acc[k] = 0.f;
  #pragma unroll 2
  for (int t = start; t < end; t++) {
    int node = cidx[t];
    size_t hi = (size_t)node*HC1 + chg;
    float hv = bf2f(hhr[hi]) + bf2f(hlr[hi]);
    const float* cp = cluster_id + (size_t)node*NCLU + cq*16;
    float4 c0 = *(const float4*)cp,     c1 = *(const float4*)(cp+4);
    float4 c2 = *(const float4*)(cp+8), c3 = *(const float4*)(cp+12);
    acc[0]  = fmaf(c0.x, hv, acc[0]);  acc[1]  = fmaf(c0.y, hv, acc[1]);
    acc[2]  = fmaf(c0.z, hv, acc[2]);  acc[3]  = fmaf(c0.w, hv, acc[3]);
    acc[4]  = fmaf(c1.x, hv, acc[4]);  acc[5]  = fmaf(c1.y, hv, acc[5]);
    acc[6]  = fmaf(c1.z, hv, acc[6]);  acc[7]  = fmaf(c1.w, hv, acc[7]);
    acc[8]  = fmaf(c2.x, hv, acc[8]);  acc[9]  = fmaf(c2.y, hv, acc[9]);
    acc[10] = fmaf(c2.z, hv, acc[10]); acc[11] = fmaf(c2.w, hv, acc[11]);
    acc[12] = fmaf(c3.x, hv, acc[12]); acc[13] = fmaf(c3.y, hv, acc[13]);
    acc[14] = fmaf(c3.z, hv, acc[14]); acc[15] = fmaf(c3.w, hv, acc[15]);
  }
  #pragma unroll
  for (int k = 0; k < 16; k++)
    atomicAdd(&CFraw[(size_t)(cq*16 + k)*HC1 + chg], acc[k]);
}

__global__ __launch_bounds__(256) void argmax_kernel(const float* __restrict__ cluster_id, int* __restrict__ cmax)
{
  int lane = threadIdx.x & 63;
  int i = blockIdx.x*4 + (threadIdx.x >> 6);
  float v = cluster_id[(size_t)i*NCLU + lane];
  int idx = lane;
  #pragma unroll
  for (int off = 32; off > 0; off >>= 1) {
    float ov = __shfl_xor(v, off);
    int oi = __shfl_xor(idx, off);
    if (ov > v || (ov == v && oi < idx)) { v = ov; idx = oi; }
  }
  if (lane == 0) cmax[i] = idx;
}

__global__ __launch_bounds__(256) void cfw_kernel(
    const float* __restrict__ CFraw, const float* __restrict__ colsum,
    const float* __restrict__ W2, float* __restrict__ CFW)
{
  int o = blockIdx.x*256 + threadIdx.x;     // < 64*784
  int c = o / NB2, j = o - c*NB2;
  const float* src = (j < NCOL2) ? (W2 + j) : (W2 + (size_t)512*NCOL2 + (j - NCOL2));
  float acc = 0.f;
  for (int k = 0; k < 512; k++) acc = fmaf(CFraw[(size_t)c*512 + k], src[(size_t)k*NCOL2], acc);
  CFW[o] = acc / colsum[c];
}

// ---------------- conv2 attention logits (bf16 h2) ----------------
__global__ __launch_bounds__(256) void a2_kernel(
    const u16* __restrict__ h2, const float* __restrict__ atts, const float* __restrict__ attd,
    float* __restrict__ as2, float* __restrict__ ad2)
{
  __shared__ float rows[32*NCOL2];
  __shared__ float sa[NCOL2], sd[NCOL2];
  int tid = threadIdx.x;
  size_t base = (size_t)blockIdx.x * 32 * NCOL2;
  for (int idx = tid; idx < 32*NCOL2; idx += 256) rows[idx] = bf2f(h2[base + idx]);
  for (int idx = tid; idx < NCOL2; idx += 256) { sa[idx] = atts[idx]; sd[idx] = attd[idx]; }
  __syncthreads();
  int r = tid >> 3, hd = tid & 7;
  const float* rp = rows + r*NCOL2 + hd*OUT2;
  const float* ap = sa + hd*OUT2;
  const float* dp = sd + hd*OUT2;
  float ps = 0.f, pd = 0.f;
  #pragma unroll
  for (int j = 0; j < OUT2; j++) { float v = rp[j]; ps = fmaf(v, ap[j], ps); pd = fmaf(v, dp[j], pd); }
  int node = blockIdx.x*32 + r;
  as2[node*8 + hd] = ps;
  ad2[node*8 + hd] = pd;
}

// ---------------- conv2 aggregation: head-per-lane, s folded, 4-edge unroll ----------------
__global__ __launch_bounds__(256) void agg2_kernel(
    const u16* __restrict__ h2, const float* __restrict__ p2,
    const float* __restrict__ as2, const float* __restrict__ ad2,
    const int* __restrict__ rowptr, const int* __restrict__ csr, const float* __restrict__ b2,
    float* __restrict__ out)
{
  __shared__ float red[4][NCOL2];
  int lane = threadIdx.x & 63;
  int w = threadIdx.x >> 6;
  int u = blockIdx.x*4 + w;
  int bn = (u < NNODES) ? u : u - NNODES;
  int off = u - bn;
  int rs = rowptr[bn];
  int deg = rowptr[bn+1] - rs;
  size_t pbase = (size_t)rs + (off ? NEDGES : 0);
  int hd = lane >> 3, sub = lane & 7;
  int cbase = hd*OUT2 + sub;
  float selfp = __expf(lrelu(as2[u*8 + hd] + ad2[u*8 + hd]));
  float acc[7];
  {
    const u16* own = h2 + (size_t)u*NCOL2 + cbase;
    #pragma unroll
    for (int k = 0; k < 7; k++)
      acc[k] = (sub + 8*k < OUT2) ? selfp * bf2f(own[8*k]) : 0.f;
  }
  float s = selfp;
  int j = 0;
  for (; j + 3 < deg; j += 4) {
    int s0 = csr[rs+j]   + off, s1 = csr[rs+j+1] + off;
    int s2 = csr[rs+j+2] + off, s3 = csr[rs+j+3] + off;
    float w0 = p2[(pbase+j)*8   + hd], w1 = p2[(pbase+j+1)*8 + hd];
    float w2 = p2[(pbase+j+2)*8 + hd], w3 = p2[(pbase+j+3)*8 + hd];
    const u16* r0 = h2 + (size_t)s0*NCOL2 + cbase;
    const u16* r1 = h2 + (size_t)s1*NCOL2 + cbase;
    const u16* r2 = h2 + (size_t)s2*NCOL2 + cbase;
    const u16* r3 = h2 + (size_t)s3*NCOL2 + cbase;
    #pragma unroll
    for (int k = 0; k < 7; k++) {
      if (sub + 8*k < OUT2) {
        acc[k] = fmaf(w0, bf2f(r0[8*k]), acc[k]);
        acc[k] = fmaf(w1, bf2f(r1[8*k]), acc[k]);
        acc[k] = fmaf(w2, bf2f(r2[8*k]), acc[k]);
        acc[k] = fmaf(w3, bf2f(r3[8*k]), acc[k]);
      }
    }
    s += (w0 + w1) + (w2 + w3);
  }
  for (; j < deg; j++) {
    int s0 = csr[rs+j] + off;
    float w0 = p2[(pbase+j)*8 + hd];
    const u16* r0 = h2 + (size_t)s0*NCOL2 + cbase;
    #pragma unroll
    for (int k = 0; k < 7; k++)
      if (sub + 8*k < OUT2) acc[k] = fmaf(w0, bf2f(r0[8*k]), acc[k]);
    s += w0;
  }
  float inv = 1.f / s;
  #pragma unroll
  for (int k = 0; k < 7; k++)
    if (sub + 8*k < OUT2) red[w][cbase + 8*k] = acc[k] * inv;
  __syncthreads();
  if (lane < OUT2) {
    float t = 0.f;
    #pragma unroll
    for (int h = 0; h < 8; h++) t += red[w][h*OUT2 + lane];
    out[(size_t)u*OUT2 + lane] = 0.125f*t + b2[lane];
  }
}

// ---------------- launch ----------------
extern "C" void kernel_launch(void* const* d_in, const int* in_sizes, int n_in,
                              void* d_out, int out_size, void* d_ws, size_t ws_size,
                              hipStream_t stream)
{
  (void)in_sizes; (void)n_in; (void)out_size; (void)ws_size;
  const float* x     = (const float*)d_in[0];
  const int*   ei    = (const int*)d_in[1];
  const float* cid   = (const float*)d_in[2];
  const int*   cidx  = (const int*)d_in[3];
  const float* W1    = (const float*)d_in[4];
  const float* atts1 = (const float*)d_in[5];
  const float* attd1 = (const float*)d_in[6];
  const float* b1    = (const float*)d_in[7];
  const float* W2    = (const float*)d_in[8];
  const float* atts2 = (const float*)d_in[9];
  const float* attd2 = (const float*)d_in[10];
  const float* b2    = (const float*)d_in[11];
  float* out = (float*)d_out;

  char* ws = (char*)d_ws;
  size_t off = 0;
  auto alloc = [&](size_t b){ size_t r = off; off += (b + 255) & ~(size_t)255; return r; };
  size_t o_hpre = alloc((size_t)NNODES*HC1*2);          // bf16 row-major
  size_t o_h2   = alloc((size_t)2*NNODES*NCOL2*2);      // bf16 row-major
  size_t o_xh   = alloc((size_t)64*MPAD*8*2);           // packed chunk-major
  size_t o_xl   = alloc((size_t)64*MPAD*8*2);
  size_t o_hh   = alloc((size_t)64*MPAD*8*2);
  size_t o_hl   = alloc((size_t)64*MPAD*8*2);
  size_t o_hhr  = alloc((size_t)NNODES*HC1*2);          // row-major (cf gather)
  size_t o_hlr  = alloc((size_t)NNODES*HC1*2);
  size_t o_w1h  = alloc((size_t)64*512*8*2);
  size_t o_w1l  = alloc((size_t)64*512*8*2);
  size_t o_b2h  = alloc((size_t)64*NPAD2*8*2);
  size_t o_b2l  = alloc((size_t)64*NPAD2*8*2);
  size_t o_CFW  = alloc((size_t)NCLU*NB2*4);
  size_t o_as1  = alloc((size_t)NNODES*8*4);
  size_t o_ad1  = alloc((size_t)NNODES*8*4);
  size_t o_as2  = alloc((size_t)2*NNODES*8*4);
  size_t o_ad2  = alloc((size_t)2*NNODES*8*4);
  size_t o_p1   = alloc((size_t)NEDGES*8*4);
  size_t o_p2   = alloc((size_t)2*NEDGES*8*4);
  size_t o_rp   = alloc((size_t)(NNODES+1)*4);
  size_t o_cur  = alloc((size_t)NNODES*4);
  size_t o_csr  = alloc((size_t)NEDGES*4);
  size_t o_dst  = alloc((size_t)NEDGES*4);
  size_t o_cmax = alloc((size_t)NNODES*4);
  size_t o_cnt  = alloc((size_t)NNODES*4);
  size_t o_csum = alloc(256 + (size_t)NCLU*HC1*4);

  u16*   hpre  = (u16*)(ws + o_hpre);
  u16*   h2    = (u16*)(ws + o_h2);
  u16*   xh    = (u16*)(ws + o_xh);
  u16*   xl    = (u16*)(ws + o_xl);
  u16*   hh    = (u16*)(ws + o_hh);
  u16*   hl    = (u16*)(ws + o_hl);
  u16*   hhr   = (u16*)(ws + o_hhr);
  u16*   hlr   = (u16*)(ws + o_hlr);
  u16*   w1h   = (u16*)(ws + o_w1h);
  u16*   w1l   = (u16*)(ws + o_w1l);
  u16*   b2h   = (u16*)(ws + o_b2h);
  u16*   b2l   = (u16*)(ws + o_b2l);
  float* CFW   = (float*)(ws + o_CFW);
  float* as1   = (float*)(ws + o_as1);
  float* ad1   = (float*)(ws + o_ad1);
  float* as2   = (float*)(ws + o_as2);
  float* ad2   = (float*)(ws + o_ad2);
  float* p1    = (float*)(ws + o_p1);
  float* p2    = (float*)(ws + o_p2);
  int*   rp    = (int*)(ws + o_rp);
  int*   cur   = (int*)(ws + o_cur);
  int*   csr   = (int*)(ws + o_csr);
  int*   dstid = (int*)(ws + o_dst);
  int*   cmax  = (int*)(ws + o_cmax);
  int*   cnt   = (int*)(ws + o_cnt);
  float* colsum= (float*)(ws + o_csum);
  float* CFraw = (float*)(ws + o_csum + 256);

  hipMemsetAsync(ws + o_cnt, 0, (size_t)NNODES*4, stream);
  hipMemsetAsync(ws + o_csum, 0, 256 + (size_t)NCLU*HC1*4, stream);

  // repack/split inputs
  split4_kernel<<<5000, 256, 0, stream>>>(x, xh, xl);
  tw1_kernel<<<128, 256, 0, stream>>>(W1, w1h, w1l);
  tb2_kernel<<<224, 256, 0, stream>>>(W2, b2h, b2l);
  // CSR (shared by both convs)
  hist_kernel<<<1250, 256, 0, stream>>>(ei, cnt);
  scan_kernel<<<1, 1024, 0, stream>>>(cnt, rp, cur);
  scatter_kernel<<<1250, 256, 0, stream>>>(ei, cur, csr, dstid);
  // conv1 linear (dbuf async-staged MFMA) -> bf16 hpre
  gemm_mfma<0><<<dim3(157,4), 256, 0, stream>>>(xh, xl, w1h, w1l, MPAD, 512, hpre, NNODES, 512, nullptr, nullptr, nullptr);
  // conv1 attention
  a1_kernel<<<5000, 256, 0, stream>>>(hpre, atts1, attd1, as1, ad1);
  exp1_kernel<<<1250, 256, 0, stream>>>(csr, dstid, as1, ad1, p1);
  agg1_kernel<<<5000, 256, 0, stream>>>(hpre, p1, as1, ad1, rp, csr, b1, hhr, hlr, hh, hl);
  // cluster features
  colsum_kernel<<<32, 256, 0, stream>>>(cid, cidx, colsum);
  cf_kernel<<<dim3(8,25), 256, 0, stream>>>(cid, cidx, hhr, hlr, CFraw);
  argmax_kernel<<<5000, 256, 0, stream>>>(cid, cmax);
  cfw_kernel<<<196, 256, 0, stream>>>(CFraw, colsum, W2, CFW);
  // conv2 linear (dbuf) -> bf16 h2 [2N,392] with fused x1-add
  gemm_mfma<1><<<dim3(157,7), 256, 0, stream>>>(hh, hl, b2h, b2l, MPAD, NPAD2, nullptr, NNODES, NB2, cmax, CFW, h2);
  // conv2 attention
  a2_kernel<<<1250, 256, 0, stream>>>(h2, atts2, attd2, as2, ad2);
  exp2_kernel<<<2500, 256, 0, stream>>>(csr, dstid, as2, ad2, p2);
  agg2_kernel<<<10000, 256, 0, stream>>>(h2, p2, as2, ad2, rp, csr, b2, out);
}

// Round 9
// 669.016 us; speedup vs baseline: 1.0358x; 1.0358x over previous
//
#include <hip/hip_runtime.h>

#define NNODES 20000
#define MPAD   20096    // NNODES padded to multiple of 128
#define NEDGES 320000
#define FIN    512
#define HC1    512      // H1*HID
#define NHEAD  8
#define OUT2   49
#define NCOL2  392      // NHEAD*OUT2
#define NB2    784      // 2*NCOL2
#define NPAD2  896      // NB2 padded to multiple of 128
#define NCLU   64
#define NIDX   10000
#define NEG    0.2f

typedef unsigned short u16;
typedef short bf16x8 __attribute__((ext_vector_type(8)));
typedef float f32x4 __attribute__((ext_vector_type(4)));

static __device__ __forceinline__ float lrelu(float v){ return v > 0.f ? v : NEG*v; }

// exact split (truncation): f = hi + rem
static __device__ __forceinline__ u16 f2bf_hi(float f, float& rem) {
  union { float f; unsigned u; } c; c.f = f;
  unsigned hb = c.u & 0xFFFF0000u;
  union { unsigned u; float f; } d; d.u = hb;
  rem = f - d.f;
  return (u16)(hb >> 16);
}
static __device__ __forceinline__ u16 f2bf(float f) {   // truncate
  union { float f; unsigned u; } c; c.f = f;
  return (u16)(c.u >> 16);
}
static __device__ __forceinline__ u16 f2bf_rn(float f) { // round-nearest-even
  union { float f; unsigned u; } c; c.f = f;
  unsigned r = c.u + 0x7FFFu + ((c.u >> 16) & 1u);
  return (u16)(r >> 16);
}
static __device__ __forceinline__ float bf2f(u16 u) {
  union { unsigned u; float f; } c; c.u = ((unsigned)u) << 16;
  return c.f;
}
static __device__ __forceinline__ void load8bf(const u16* p, float* o) {
  ushort4 a = *(const ushort4*)p;
  ushort4 b = *(const ushort4*)(p + 4);
  o[0]=bf2f(a.x); o[1]=bf2f(a.y); o[2]=bf2f(a.z); o[3]=bf2f(a.w);
  o[4]=bf2f(b.x); o[5]=bf2f(b.y); o[6]=bf2f(b.z); o[7]=bf2f(b.w);
}

// async 16B global->LDS
typedef __attribute__((address_space(3))) unsigned int lds_u32;
typedef __attribute__((address_space(1))) const unsigned int glb_u32;
static __device__ __forceinline__ void gl_lds16(const u16* g, u16* l) {
  __builtin_amdgcn_global_load_lds((glb_u32*)g, (lds_u32*)l, 16, 0, 0);
}

// ---------------- split x -> packed [kc][row][8], coalesced both sides via LDS ----------------
__global__ __launch_bounds__(256) void split4_kernel(const float* __restrict__ x,
                                                     u16* __restrict__ xh, u16* __restrict__ xl) {
  __shared__ __align__(16) u16 th[4][512], tl[4][512];
  int wv = threadIdx.x >> 6;
  int lane = threadIdx.x & 63;
  int i = blockIdx.x*4 + wv;
  const float* p = x + (size_t)i*FIN + lane*8;
  float4 v0 = *(const float4*)p, v1 = *(const float4*)(p+4);
  float rem; ushort4 h0,h1,l0,l1;
  h0.x = f2bf_hi(v0.x, rem); l0.x = f2bf(rem);
  h0.y = f2bf_hi(v0.y, rem); l0.y = f2bf(rem);
  h0.z = f2bf_hi(v0.z, rem); l0.z = f2bf(rem);
  h0.w = f2bf_hi(v0.w, rem); l0.w = f2bf(rem);
  h1.x = f2bf_hi(v1.x, rem); l1.x = f2bf(rem);
  h1.y = f2bf_hi(v1.y, rem); l1.y = f2bf(rem);
  h1.z = f2bf_hi(v1.z, rem); l1.z = f2bf(rem);
  h1.w = f2bf_hi(v1.w, rem); l1.w = f2bf(rem);
  *(ushort4*)&th[wv][lane*8]   = h0; *(ushort4*)&th[wv][lane*8+4] = h1;
  *(ushort4*)&tl[wv][lane*8]   = l0; *(ushort4*)&tl[wv][lane*8+4] = l1;
  __syncthreads();
  int kc = threadIdx.x >> 2, nd = threadIdx.x & 3;
  size_t o = ((size_t)kc*MPAD + blockIdx.x*4 + nd)*8;
  *(uint4*)&xh[o] = *(const uint4*)&th[nd][kc*8];
  *(uint4*)&xl[o] = *(const uint4*)&tl[nd][kc*8];
}

__global__ void tw1_kernel(const float* __restrict__ W1, u16* __restrict__ Th, u16* __restrict__ Tl) {
  int tid = blockIdx.x*256 + threadIdx.x;   // < 64*512
  int kc = tid >> 9, j = tid & 511;
  float rem; ushort4 h0,h1,l0,l1;
  h0.x = f2bf_hi(W1[(size_t)(kc*8+0)*512 + j], rem); l0.x = f2bf(rem);
  h0.y = f2bf_hi(W1[(size_t)(kc*8+1)*512 + j], rem); l0.y = f2bf(rem);
  h0.z = f2bf_hi(W1[(size_t)(kc*8+2)*512 + j], rem); l0.z = f2bf(rem);
  h0.w = f2bf_hi(W1[(size_t)(kc*8+3)*512 + j], rem); l0.w = f2bf(rem);
  h1.x = f2bf_hi(W1[(size_t)(kc*8+4)*512 + j], rem); l1.x = f2bf(rem);
  h1.y = f2bf_hi(W1[(size_t)(kc*8+5)*512 + j], rem); l1.y = f2bf(rem);
  h1.z = f2bf_hi(W1[(size_t)(kc*8+6)*512 + j], rem); l1.z = f2bf(rem);
  h1.w = f2bf_hi(W1[(size_t)(kc*8+7)*512 + j], rem); l1.w = f2bf(rem);
  size_t o = ((size_t)kc*512 + j)*8;
  *(ushort4*)&Th[o] = h0; *(ushort4*)&Th[o+4] = h1;
  *(ushort4*)&Tl[o] = l0; *(ushort4*)&Tl[o+4] = l1;
}

__global__ void tb2_kernel(const float* __restrict__ W2, u16* __restrict__ Th, u16* __restrict__ Tl) {
  int tid = blockIdx.x*256 + threadIdx.x;   // < 64*896
  int kc = tid / NPAD2, j = tid - kc*NPAD2;
  float v[8];
  #pragma unroll
  for (int e = 0; e < 8; e++) {
    int k = kc*8 + e;
    v[e] = (j < NCOL2) ? W2[(size_t)k*NCOL2 + j]
         : ((j < NB2) ? W2[(size_t)(512+k)*NCOL2 + (j - NCOL2)] : 0.f);
  }
  float rem; ushort4 h0,h1,l0,l1;
  h0.x = f2bf_hi(v[0], rem); l0.x = f2bf(rem);
  h0.y = f2bf_hi(v[1], rem); l0.y = f2bf(rem);
  h0.z = f2bf_hi(v[2], rem); l0.z = f2bf(rem);
  h0.w = f2bf_hi(v[3], rem); l0.w = f2bf(rem);
  h1.x = f2bf_hi(v[4], rem); l1.x = f2bf(rem);
  h1.y = f2bf_hi(v[5], rem); l1.y = f2bf(rem);
  h1.z = f2bf_hi(v[6], rem); l1.z = f2bf(rem);
  h1.w = f2bf_hi(v[7], rem); l1.w = f2bf(rem);
  size_t o = ((size_t)kc*NPAD2 + j)*8;
  *(ushort4*)&Th[o] = h0; *(ushort4*)&Th[o+4] = h1;
  *(ushort4*)&Tl[o] = l0; *(ushort4*)&Tl[o+4] = l1;
}

// ---------------- split-bf16 MFMA GEMM: double-buffered async staging, 1 barrier/iter ----------------
template<int EPI>
__global__ __launch_bounds__(256) void gemm_mfma(
    const u16* __restrict__ Ah, const u16* __restrict__ Al,
    const u16* __restrict__ Bh, const u16* __restrict__ Bl,
    int Apitch, int Bpitch,
    u16* __restrict__ Cbf, int M, int Ncols,
    const int* __restrict__ cmax, const float* __restrict__ CFW, u16* __restrict__ h2)
{
  __shared__ __align__(16) u16 S[2][16384];   // 64 KB total
  int tid = threadIdx.x;
  int lane = tid & 63;
  int w = tid >> 6;
  int row0 = blockIdx.x * 128;
  int col0 = blockIdx.y * 128;

  const u16* G; size_t pitch;
  if      (w == 0) { G = Ah + ((size_t)row0 + lane)*8; pitch = (size_t)Apitch; }
  else if (w == 1) { G = Al + ((size_t)row0 + lane)*8; pitch = (size_t)Apitch; }
  else if (w == 2) { G = Bh + ((size_t)col0 + lane)*8; pitch = (size_t)Bpitch; }
  else             { G = Bl + ((size_t)col0 + lane)*8; pitch = (size_t)Bpitch; }
  int lb = w * 4096;

  int wr = (w >> 1) * 64;
  int wc = (w & 1) * 64;
  int l16 = lane & 15;
  int q = lane >> 4;

  f32x4 acc[4][4];
  #pragma unroll
  for (int i = 0; i < 4; i++)
    #pragma unroll
    for (int j = 0; j < 4; j++)
      acc[i][j] = (f32x4){0.f, 0.f, 0.f, 0.f};

  #pragma unroll
  for (int c = 0; c < 4; c++) {
    const u16* g = G + ((size_t)c)*pitch*8;
    gl_lds16(g,       &S[0][lb + c*1024]);
    gl_lds16(g + 512, &S[0][lb + c*1024 + 512]);
  }

  for (int t = 0; t < 16; t++) {
    int cur = t & 1;
    __syncthreads();
    if (t < 15) {
      #pragma unroll
      for (int c = 0; c < 4; c++) {
        const u16* g = G + ((size_t)((t+1)*4 + c))*pitch*8;
        gl_lds16(g,       &S[1-cur][lb + c*1024]);
        gl_lds16(g + 512, &S[1-cur][lb + c*1024 + 512]);
      }
    }
    const u16* P = S[cur];
    bf16x8 ah[4], al[4], bh[4], bl[4];
    #pragma unroll
    for (int i = 0; i < 4; i++) {
      int ra = q*1024 + (wr + i*16 + l16)*8;
      int rb = q*1024 + (wc + i*16 + l16)*8;
      ah[i] = *(const bf16x8*)&P[ra];
      al[i] = *(const bf16x8*)&P[4096 + ra];
      bh[i] = *(const bf16x8*)&P[8192 + rb];
      bl[i] = *(const bf16x8*)&P[12288 + rb];
    }
    #pragma unroll
    for (int i = 0; i < 4; i++)
      #pragma unroll
      for (int j = 0; j < 4; j++)
        acc[i][j] = __builtin_amdgcn_mfma_f32_16x16x32_bf16(ah[i], bh[j], acc[i][j], 0, 0, 0);
    #pragma unroll
    for (int i = 0; i < 4; i++)
      #pragma unroll
      for (int j = 0; j < 4; j++)
        acc[i][j] = __builtin_amdgcn_mfma_f32_16x16x32_bf16(ah[i], bl[j], acc[i][j], 0, 0, 0);
    #pragma unroll
    for (int i = 0; i < 4; i++)
      #pragma unroll
      for (int j = 0; j < 4; j++)
        acc[i][j] = __builtin_amdgcn_mfma_f32_16x16x32_bf16(al[i], bh[j], acc[i][j], 0, 0, 0);
  }

  if (EPI == 0) {
    #pragma unroll
    for (int i = 0; i < 4; i++) {
      #pragma unroll
      for (int r = 0; r < 4; r++) {
        int m = row0 + wr + i*16 + q*4 + r;
        if (m < M) {
          #pragma unroll
          for (int j = 0; j < 4; j++)
            Cbf[(size_t)m*Ncols + col0 + wc + j*16 + l16] = f2bf_rn(acc[i][j][r]);
        }
      }
    }
  } else {
    #pragma unroll
    for (int i = 0; i < 4; i++) {
      #pragma unroll
      for (int r = 0; r < 4; r++) {
        int m = row0 + wr + i*16 + q*4 + r;
        if (m >= M) continue;
        int c = cmax[m];
        const float* cf = CFW + (size_t)c * NB2;
        #pragma unroll
        for (int j = 0; j < 4; j++) {
          int n = col0 + wc + j*16 + l16;
          if (n >= NB2) continue;
          float v = acc[i][j][r];
          if (n < NCOL2) h2[(size_t)m*NCOL2 + n] = f2bf_rn(v + cf[NCOL2 + n]);
          else           h2[(size_t)(NNODES + m)*NCOL2 + (n - NCOL2)] = f2bf_rn(v + cf[n - NCOL2]);
        }
      }
    }
  }
}

// ---------------- CSR build ----------------
__global__ void hist_kernel(const int* __restrict__ ei, int* __restrict__ counts) {
  int e = blockIdx.x*256 + threadIdx.x;
  if (e < NEDGES) atomicAdd(&counts[ei[NEDGES + e]], 1);
}

__global__ __launch_bounds__(1024) void scan_kernel(const int* __restrict__ counts,
                                                    int* __restrict__ rowptr, int* __restrict__ cursor) {
  __shared__ int part[1024];
  int t = threadIdx.x;
  const int CH = 20;
  int start = t*CH;
  int end = min(start+CH, NNODES);
  int sum = 0;
  for (int i = start; i < end; i++) sum += counts[i];
  part[t] = sum;
  __syncthreads();
  for (int off = 1; off < 1024; off <<= 1) {
    int v = part[t];
    int add = (t >= off) ? part[t-off] : 0;
    __syncthreads();
    part[t] = v + add;
    __syncthreads();
  }
  int run = part[t] - sum;
  for (int i = start; i < end; i++) {
    rowptr[i] = run; cursor[i] = run;
    run += counts[i];
  }
  if (t == 1023) rowptr[NNODES] = part[1023];
}

__global__ void scatter_kernel(const int* __restrict__ ei, int* __restrict__ cursor,
                               int* __restrict__ csr, int* __restrict__ dstid) {
  int e = blockIdx.x*256 + threadIdx.x;
  if (e < NEDGES) {
    int src = ei[e];
    int dst = ei[NEDGES + e];
    int pos = atomicAdd(&cursor[dst], 1);
    csr[pos] = src;
    dstid[pos] = dst;
  }
}

// ---------------- conv1 attention logits (bf16 hpre row-major) ----------------
__global__ __launch_bounds__(256) void a1_kernel(
    const u16* __restrict__ hpre, const float* __restrict__ atts, const float* __restrict__ attd,
    float* __restrict__ as1, float* __restrict__ ad1)
{
  int lane = threadIdx.x & 63;
  int i = blockIdx.x*4 + (threadIdx.x >> 6);
  float hv[8];
  load8bf(hpre + (size_t)i*HC1 + lane*8, hv);
  const float* ap = atts + lane*8; const float* dp = attd + lane*8;
  float ps = 0.f, pd = 0.f;
  #pragma unroll
  for (int k = 0; k < 8; k++) { ps = fmaf(hv[k], ap[k], ps); pd = fmaf(hv[k], dp[k], pd); }
  ps += __shfl_down(ps, 4, 8); ps += __shfl_down(ps, 2, 8); ps += __shfl_down(ps, 1, 8);
  pd += __shfl_down(pd, 4, 8); pd += __shfl_down(pd, 2, 8); pd += __shfl_down(pd, 1, 8);
  if ((lane & 7) == 0) {
    as1[i*8 + (lane >> 3)] = ps;
    ad1[i*8 + (lane >> 3)] = pd;
  }
}

// ---------------- edge-parallel exp kernels (denominator folded into agg) ----------------
__global__ void exp1_kernel(const int* __restrict__ csr, const int* __restrict__ dstid,
                            const float* __restrict__ as1, const float* __restrict__ ad1,
                            float* __restrict__ p1)
{
  int pos = blockIdx.x*256 + threadIdx.x;   // grid exact: E
  int src = csr[pos], dst = dstid[pos];
  const float* a = as1 + (size_t)src*8;
  const float* d = ad1 + (size_t)dst*8;
  float4 a0 = *(const float4*)a, a1v = *(const float4*)(a+4);
  float4 d0 = *(const float4*)d, d1v = *(const float4*)(d+4);
  float4 o0, o1;
  o0.x = __expf(lrelu(a0.x + d0.x));  o0.y = __expf(lrelu(a0.y + d0.y));
  o0.z = __expf(lrelu(a0.z + d0.z));  o0.w = __expf(lrelu(a0.w + d0.w));
  o1.x = __expf(lrelu(a1v.x + d1v.x)); o1.y = __expf(lrelu(a1v.y + d1v.y));
  o1.z = __expf(lrelu(a1v.z + d1v.z)); o1.w = __expf(lrelu(a1v.w + d1v.w));
  *(float4*)(p1 + (size_t)pos*8)     = o0;
  *(float4*)(p1 + (size_t)pos*8 + 4) = o1;
}

__global__ void exp2_kernel(const int* __restrict__ csr, const int* __restrict__ dstid,
                            const float* __restrict__ as2, const float* __restrict__ ad2,
                            float* __restrict__ p2)
{
  int pos2 = blockIdx.x*256 + threadIdx.x;  // grid exact: 2E
  int half = (pos2 >= NEDGES) ? 1 : 0;
  int pos = pos2 - half*NEDGES;
  int src = csr[pos] + half*NNODES;
  int dst = dstid[pos] + half*NNODES;
  const float* a = as2 + (size_t)src*8;
  const float* d = ad2 + (size_t)dst*8;
  float4 a0 = *(const float4*)a, a1v = *(const float4*)(a+4);
  float4 d0 = *(const float4*)d, d1v = *(const float4*)(d+4);
  float4 o0, o1;
  o0.x = __expf(lrelu(a0.x + d0.x));  o0.y = __expf(lrelu(a0.y + d0.y));
  o0.z = __expf(lrelu(a0.z + d0.z));  o0.w = __expf(lrelu(a0.w + d0.w));
  o1.x = __expf(lrelu(a1v.x + d1v.x)); o1.y = __expf(lrelu(a1v.y + d1v.y));
  o1.z = __expf(lrelu(a1v.z + d1v.z)); o1.w = __expf(lrelu(a1v.w + d1v.w));
  *(float4*)(p2 + (size_t)pos2*8)     = o0;
  *(float4*)(p2 + (size_t)pos2*8 + 4) = o1;
}

// ---------------- conv1 aggregation (s folded) + ELU -> row-major + packed split bf16 ----------------
__global__ __launch_bounds__(256) void agg1_kernel(
    const u16* __restrict__ hpre, const float* __restrict__ p1,
    const float* __restrict__ as1, const float* __restrict__ ad1,
    const int* __restrict__ rowptr, const int* __restrict__ csr, const float* __restrict__ b1,
    u16* __restrict__ hhr, u16* __restrict__ hlr,
    u16* __restrict__ hh, u16* __restrict__ hl)
{
  __shared__ __align__(16) u16 sh[4][512], sl[4][512];
  int lane = threadIdx.x & 63;
  int wv = threadIdx.x >> 6;
  int i = blockIdx.x*4 + wv;
  int hd = lane >> 3;
  int rs = rowptr[i];
  int deg = rowptr[i+1] - rs;
  float selfp = __expf(lrelu(as1[i*8 + hd] + ad1[i*8 + hd]));
  float acc[8];
  {
    float v[8];
    load8bf(hpre + (size_t)i*HC1 + lane*8, v);
    #pragma unroll
    for (int k = 0; k < 8; k++) acc[k] = selfp * v[k];
  }
  float s = selfp;
  int j = 0;
  for (; j + 1 < deg; j += 2) {
    int s0 = csr[rs+j], s1 = csr[rs+j+1];
    float w0 = p1[(size_t)(rs+j)*8 + hd];
    float w1 = p1[(size_t)(rs+j+1)*8 + hd];
    float v0[8], v1[8];
    load8bf(hpre + (size_t)s0*HC1 + lane*8, v0);
    load8bf(hpre + (size_t)s1*HC1 + lane*8, v1);
    #pragma unroll
    for (int k = 0; k < 8; k++) acc[k] = fmaf(w0, v0[k], acc[k]);
    #pragma unroll
    for (int k = 0; k < 8; k++) acc[k] = fmaf(w1, v1[k], acc[k]);
    s += w0 + w1;
  }
  if (j < deg) {
    int s0 = csr[rs+j];
    float w0 = p1[(size_t)(rs+j)*8 + hd];
    float v0[8];
    load8bf(hpre + (size_t)s0*HC1 + lane*8, v0);
    #pragma unroll
    for (int k = 0; k < 8; k++) acc[k] = fmaf(w0, v0[k], acc[k]);
    s += w0;
  }
  float inv = 1.f / s;
  float rem; ushort4 h0,h1,l0,l1;
  float o[8];
  #pragma unroll
  for (int k = 0; k < 8; k++) {
    float v = acc[k]*inv + b1[lane*8 + k];
    o[k] = v > 0.f ? v : __expf(v) - 1.f;   // ELU
  }
  h0.x = f2bf_hi(o[0], rem); l0.x = f2bf(rem);
  h0.y = f2bf_hi(o[1], rem); l0.y = f2bf(rem);
  h0.z = f2bf_hi(o[2], rem); l0.z = f2bf(rem);
  h0.w = f2bf_hi(o[3], rem); l0.w = f2bf(rem);
  h1.x = f2bf_hi(o[4], rem); l1.x = f2bf(rem);
  h1.y = f2bf_hi(o[5], rem); l1.y = f2bf(rem);
  h1.z = f2bf_hi(o[6], rem); l1.z = f2bf(rem);
  h1.w = f2bf_hi(o[7], rem); l1.w = f2bf(rem);
  size_t rb = (size_t)i*HC1 + lane*8;
  *(ushort4*)&hhr[rb]   = h0; *(ushort4*)&hhr[rb+4] = h1;
  *(ushort4*)&hlr[rb]   = l0; *(ushort4*)&hlr[rb+4] = l1;
  *(ushort4*)&sh[wv][lane*8]   = h0; *(ushort4*)&sh[wv][lane*8+4] = h1;
  *(ushort4*)&sl[wv][lane*8]   = l0; *(ushort4*)&sl[wv][lane*8+4] = l1;
  __syncthreads();
  int kc = threadIdx.x >> 2, nd = threadIdx.x & 3;
  size_t po = ((size_t)kc*MPAD + blockIdx.x*4 + nd)*8;
  *(uint4*)&hh[po] = *(const uint4*)&sh[nd][kc*8];
  *(uint4*)&hl[po] = *(const uint4*)&sl[nd][kc*8];
}

// ---------------- cluster stage ----------------
__global__ __launch_bounds__(256) void colsum_kernel(
    const float* __restrict__ cluster_id, const int* __restrict__ cidx, float* __restrict__ colsum)
{
  __shared__ float part[4][64];
  int tid = threadIdx.x; int q = tid >> 6, col = tid & 63;
  int start = blockIdx.x*313, end = min(start+313, NIDX);
  float acc = 0.f;
  for (int t = start + q; t < end; t += 4) {
    int node = cidx[t];
    acc += cluster_id[(size_t)node*NCLU + col];
  }
  part[q][col] = acc;
  __syncthreads();
  if (tid < 64) {
    float v = part[0][tid] + part[1][tid] + part[2][tid] + part[3][tid];
    atomicAdd(&colsum[tid], v);
  }
}

// CFraw[c][ch] += cid[node][c]*h[node][ch]; grid (8 ch-slices, 100 t-chunks), 4-way unrolled gather
__global__ __launch_bounds__(256) void cf_kernel(
    const float* __restrict__ cluster_id, const int* __restrict__ cidx,
    const u16* __restrict__ hhr, const u16* __restrict__ hlr, float* __restrict__ CFraw)
{
  int chl = threadIdx.x & 63;
  int cq  = threadIdx.x >> 6;
  int chg = blockIdx.x*64 + chl;
  int start = blockIdx.y*100;               // 100 blocks.y * 100 = NIDX
  float acc[16];
  #pragma unroll
  for (int k = 0; k < 16; k++) acc[k] = 0.f;
  for (int t = start; t < start + 100; t += 4) {
    int4 nd = *(const int4*)(cidx + t);     // 4 indices at once
    size_t i0 = (size_t)nd.x*HC1 + chg, i1 = (size_t)nd.y*HC1 + chg;
    size_t i2 = (size_t)nd.z*HC1 + chg, i3 = (size_t)nd.w*HC1 + chg;
    u16 h0 = hhr[i0], h1 = hhr[i1], h2v = hhr[i2], h3 = hhr[i3];
    u16 g0 = hlr[i0], g1 = hlr[i1], g2 = hlr[i2], g3 = hlr[i3];
    const float* cp0 = cluster_id + (size_t)nd.x*NCLU + cq*16;
    const float* cp1 = cluster_id + (size_t)nd.y*NCLU + cq*16;
    const float* cp2 = cluster_id + (size_t)nd.z*NCLU + cq*16;
    const float* cp3 = cluster_id + (size_t)nd.w*NCLU + cq*16;
    float hv0 = bf2f(h0)+bf2f(g0), hv1 = bf2f(h1)+bf2f(g1);
    float hv2 = bf2f(h2v)+bf2f(g2), hv3 = bf2f(h3)+bf2f(g3);
    #pragma unroll
    for (int q4 = 0; q4 < 4; q4++) {
      float4 c0 = *(const float4*)(cp0 + q4*4);
      float4 c1 = *(const float4*)(cp1 + q4*4);
      float4 c2 = *(const float4*)(cp2 + q4*4);
      float4 c3 = *(const float4*)(cp3 + q4*4);
      acc[q4*4+0] = fmaf(c0.x, hv0, fmaf(c1.x, hv1, fmaf(c2.x, hv2, fmaf(c3.x, hv3, acc[q4*4+0]))));
      acc[q4*4+1] = fmaf(c0.y, hv0, fmaf(c1.y, hv1, fmaf(c2.y, hv2, fmaf(c3.y, hv3, acc[q4*4+1]))));
      acc[q4*4+2] = fmaf(c0.z, hv0, fmaf(c1.z, hv1, fmaf(c2.z, hv2, fmaf(c3.z, hv3, acc[q4*4+2]))));
      acc[q4*4+3] = fmaf(c0.w, hv0, fmaf(c1.w, hv1, fmaf(c2.w, hv2, fmaf(c3.w, hv3, acc[q4*4+3]))));
    }
  }
  #pragma unroll
  for (int k = 0; k < 16; k++)
    atomicAdd(&CFraw[(size_t)(cq*16 + k)*HC1 + chg], acc[k]);
}

__global__ __launch_bounds__(256) void argmax_kernel(const float* __restrict__ cluster_id, int* __restrict__ cmax)
{
  int lane = threadIdx.x & 63;
  int i = blockIdx.x*4 + (threadIdx.x >> 6);
  float v = cluster_id[(size_t)i*NCLU + lane];
  int idx = lane;
  #pragma unroll
  for (int off = 32; off > 0; off >>= 1) {
    float ov = __shfl_xor(v, off);
    int oi = __shfl_xor(idx, off);
    if (ov > v || (ov == v && oi < idx)) { v = ov; idx = oi; }
  }
  if (lane == 0) cmax[i] = idx;
}

__global__ __launch_bounds__(256) void cfw_kernel(
    const float* __restrict__ CFraw, const float* __restrict__ colsum,
    const float* __restrict__ W2, float* __restrict__ CFW)
{
  int o = blockIdx.x*256 + threadIdx.x;     // < 64*784
  int c = o / NB2, j = o - c*NB2;
  const float* src = (j < NCOL2) ? (W2 + j) : (W2 + (size_t)512*NCOL2 + (j - NCOL2));
  float acc = 0.f;
  for (int k = 0; k < 512; k++) acc = fmaf(CFraw[(size_t)c*512 + k], src[(size_t)k*NCOL2], acc);
  CFW[o] = acc / colsum[c];
}

// ---------------- conv2 attention logits (bf16 h2) ----------------
__global__ __launch_bounds__(256) void a2_kernel(
    const u16* __restrict__ h2, const float* __restrict__ atts, const float* __restrict__ attd,
    float* __restrict__ as2, float* __restrict__ ad2)
{
  __shared__ float rows[32*NCOL2];
  __shared__ float sa[NCOL2], sd[NCOL2];
  int tid = threadIdx.x;
  size_t base = (size_t)blockIdx.x * 32 * NCOL2;
  for (int idx = tid; idx < 32*NCOL2; idx += 256) rows[idx] = bf2f(h2[base + idx]);
  for (int idx = tid; idx < NCOL2; idx += 256) { sa[idx] = atts[idx]; sd[idx] = attd[idx]; }
  __syncthreads();
  int r = tid >> 3, hd = tid & 7;
  const float* rp = rows + r*NCOL2 + hd*OUT2;
  const float* ap = sa + hd*OUT2;
  const float* dp = sd + hd*OUT2;
  float ps = 0.f, pd = 0.f;
  #pragma unroll
  for (int j = 0; j < OUT2; j++) { float v = rp[j]; ps = fmaf(v, ap[j], ps); pd = fmaf(v, dp[j], pd); }
  int node = blockIdx.x*32 + r;
  as2[node*8 + hd] = ps;
  ad2[node*8 + hd] = pd;
}

// ---------------- conv2 aggregation: head-per-lane, s folded, 4-edge unroll ----------------
__global__ __launch_bounds__(256) void agg2_kernel(
    const u16* __restrict__ h2, const float* __restrict__ p2,
    const float* __restrict__ as2, const float* __restrict__ ad2,
    const int* __restrict__ rowptr, const int* __restrict__ csr, const float* __restrict__ b2,
    float* __restrict__ out)
{
  __shared__ float red[4][NCOL2];
  int lane = threadIdx.x & 63;
  int w = threadIdx.x >> 6;
  int u = blockIdx.x*4 + w;
  int bn = (u < NNODES) ? u : u - NNODES;
  int off = u - bn;
  int rs = rowptr[bn];
  int deg = rowptr[bn+1] - rs;
  size_t pbase = (size_t)rs + (off ? NEDGES : 0);
  int hd = lane >> 3, sub = lane & 7;
  int cbase = hd*OUT2 + sub;
  float selfp = __expf(lrelu(as2[u*8 + hd] + ad2[u*8 + hd]));
  float acc[7];
  {
    const u16* own = h2 + (size_t)u*NCOL2 + cbase;
    #pragma unroll
    for (int k = 0; k < 7; k++)
      acc[k] = (sub + 8*k < OUT2) ? selfp * bf2f(own[8*k]) : 0.f;
  }
  float s = selfp;
  int j = 0;
  for (; j + 3 < deg; j += 4) {
    int s0 = csr[rs+j]   + off, s1 = csr[rs+j+1] + off;
    int s2 = csr[rs+j+2] + off, s3 = csr[rs+j+3] + off;
    float w0 = p2[(pbase+j)*8   + hd], w1 = p2[(pbase+j+1)*8 + hd];
    float w2 = p2[(pbase+j+2)*8 + hd], w3 = p2[(pbase+j+3)*8 + hd];
    const u16* r0 = h2 + (size_t)s0*NCOL2 + cbase;
    const u16* r1 = h2 + (size_t)s1*NCOL2 + cbase;
    const u16* r2 = h2 + (size_t)s2*NCOL2 + cbase;
    const u16* r3 = h2 + (size_t)s3*NCOL2 + cbase;
    #pragma unroll
    for (int k = 0; k < 7; k++) {
      if (sub + 8*k < OUT2) {
        acc[k] = fmaf(w0, bf2f(r0[8*k]), acc[k]);
        acc[k] = fmaf(w1, bf2f(r1[8*k]), acc[k]);
        acc[k] = fmaf(w2, bf2f(r2[8*k]), acc[k]);
        acc[k] = fmaf(w3, bf2f(r3[8*k]), acc[k]);
      }
    }
    s += (w0 + w1) + (w2 + w3);
  }
  for (; j < deg; j++) {
    int s0 = csr[rs+j] + off;
    float w0 = p2[(pbase+j)*8 + hd];
    const u16* r0 = h2 + (size_t)s0*NCOL2 + cbase;
    #pragma unroll
    for (int k = 0; k < 7; k++)
      if (sub + 8*k < OUT2) acc[k] = fmaf(w0, bf2f(r0[8*k]), acc[k]);
    s += w0;
  }
  float inv = 1.f / s;
  #pragma unroll
  for (int k = 0; k < 7; k++)
    if (sub + 8*k < OUT2) red[w][cbase + 8*k] = acc[k] * inv;
  __syncthreads();
  if (lane < OUT2) {
    float t = 0.f;
    #pragma unroll
    for (int h = 0; h < 8; h++) t += red[w][h*OUT2 + lane];
    out[(size_t)u*OUT2 + lane] = 0.125f*t + b2[lane];
  }
}

// ---------------- launch ----------------
extern "C" void kernel_launch(void* const* d_in, const int* in_sizes, int n_in,
                              void* d_out, int out_size, void* d_ws, size_t ws_size,
                              hipStream_t stream)
{
  (void)in_sizes; (void)n_in; (void)out_size; (void)ws_size;
  const float* x     = (const float*)d_in[0];
  const int*   ei    = (const int*)d_in[1];
  const float* cid   = (const float*)d_in[2];
  const int*   cidx  = (const int*)d_in[3];
  const float* W1    = (const float*)d_in[4];
  const float* atts1 = (const float*)d_in[5];
  const float* attd1 = (const float*)d_in[6];
  const float* b1    = (const float*)d_in[7];
  const float* W2    = (const float*)d_in[8];
  const float* atts2 = (const float*)d_in[9];
  const float* attd2 = (const float*)d_in[10];
  const float* b2    = (const float*)d_in[11];
  float* out = (float*)d_out;

  char* ws = (char*)d_ws;
  size_t off = 0;
  auto alloc = [&](size_t b){ size_t r = off; off += (b + 255) & ~(size_t)255; return r; };
  size_t o_hpre = alloc((size_t)NNODES*HC1*2);          // bf16 row-major
  size_t o_h2   = alloc((size_t)2*NNODES*NCOL2*2);      // bf16 row-major
  size_t o_xh   = alloc((size_t)64*MPAD*8*2);           // packed chunk-major
  size_t o_xl   = alloc((size_t)64*MPAD*8*2);
  size_t o_hh   = alloc((size_t)64*MPAD*8*2);
  size_t o_hl   = alloc((size_t)64*MPAD*8*2);
  size_t o_hhr  = alloc((size_t)NNODES*HC1*2);          // row-major (cf gather)
  size_t o_hlr  = alloc((size_t)NNODES*HC1*2);
  size_t o_w1h  = alloc((size_t)64*512*8*2);
  size_t o_w1l  = alloc((size_t)64*512*8*2);
  size_t o_b2h  = alloc((size_t)64*NPAD2*8*2);
  size_t o_b2l  = alloc((size_t)64*NPAD2*8*2);
  size_t o_CFW  = alloc((size_t)NCLU*NB2*4);
  size_t o_as1  = alloc((size_t)NNODES*8*4);
  size_t o_ad1  = alloc((size_t)NNODES*8*4);
  size_t o_as2  = alloc((size_t)2*NNODES*8*4);
  size_t o_ad2  = alloc((size_t)2*NNODES*8*4);
  size_t o_p1   = alloc((size_t)NEDGES*8*4);
  size_t o_p2   = alloc((size_t)2*NEDGES*8*4);
  size_t o_rp   = alloc((size_t)(NNODES+1)*4);
  size_t o_cur  = alloc((size_t)NNODES*4);
  size_t o_csr  = alloc((size_t)NEDGES*4);
  size_t o_dst  = alloc((size_t)NEDGES*4);
  size_t o_cmax = alloc((size_t)NNODES*4);
  size_t o_cnt  = alloc((size_t)NNODES*4);
  size_t o_csum = alloc(256 + (size_t)NCLU*HC1*4);

  u16*   hpre  = (u16*)(ws + o_hpre);
  u16*   h2    = (u16*)(ws + o_h2);
  u16*   xh    = (u16*)(ws + o_xh);
  u16*   xl    = (u16*)(ws + o_xl);
  u16*   hh    = (u16*)(ws + o_hh);
  u16*   hl    = (u16*)(ws + o_hl);
  u16*   hhr   = (u16*)(ws + o_hhr);
  u16*   hlr   = (u16*)(ws + o_hlr);
  u16*   w1h   = (u16*)(ws + o_w1h);
  u16*   w1l   = (u16*)(ws + o_w1l);
  u16*   b2h   = (u16*)(ws + o_b2h);
  u16*   b2l   = (u16*)(ws + o_b2l);
  float* CFW   = (float*)(ws + o_CFW);
  float* as1   = (float*)(ws + o_as1);
  float* ad1   = (float*)(ws + o_ad1);
  float* as2   = (float*)(ws + o_as2);
  float* ad2   = (float*)(ws + o_ad2);
  float* p1    = (float*)(ws + o_p1);
  float* p2    = (float*)(ws + o_p2);
  int*   rp    = (int*)(ws + o_rp);
  int*   cur   = (int*)(ws + o_cur);
  int*   csr   = (int*)(ws + o_csr);
  int*   dstid = (int*)(ws + o_dst);
  int*   cmax  = (int*)(ws + o_cmax);
  int*   cnt   = (int*)(ws + o_cnt);
  float* colsum= (float*)(ws + o_csum);
  float* CFraw = (float*)(ws + o_csum + 256);

  hipMemsetAsync(ws + o_cnt, 0, (size_t)NNODES*4, stream);
  hipMemsetAsync(ws + o_csum, 0, 256 + (size_t)NCLU*HC1*4, stream);

  // repack/split inputs
  split4_kernel<<<5000, 256, 0, stream>>>(x, xh, xl);
  tw1_kernel<<<128, 256, 0, stream>>>(W1, w1h, w1l);
  tb2_kernel<<<224, 256, 0, stream>>>(W2, b2h, b2l);
  // CSR (shared by both convs)
  hist_kernel<<<1250, 256, 0, stream>>>(ei, cnt);
  scan_kernel<<<1, 1024, 0, stream>>>(cnt, rp, cur);
  scatter_kernel<<<1250, 256, 0, stream>>>(ei, cur, csr, dstid);
  // conv1 linear (dbuf async-staged MFMA) -> bf16 hpre
  gemm_mfma<0><<<dim3(157,4), 256, 0, stream>>>(xh, xl, w1h, w1l, MPAD, 512, hpre, NNODES, 512, nullptr, nullptr, nullptr);
  // conv1 attention
  a1_kernel<<<5000, 256, 0, stream>>>(hpre, atts1, attd1, as1, ad1);
  exp1_kernel<<<1250, 256, 0, stream>>>(csr, dstid, as1, ad1, p1);
  agg1_kernel<<<5000, 256, 0, stream>>>(hpre, p1, as1, ad1, rp, csr, b1, hhr, hlr, hh, hl);
  // cluster features
  colsum_kernel<<<32, 256, 0, stream>>>(cid, cidx, colsum);
  cf_kernel<<<dim3(8,100), 256, 0, stream>>>(cid, cidx, hhr, hlr, CFraw);
  argmax_kernel<<<5000, 256, 0, stream>>>(cid, cmax);
  cfw_kernel<<<196, 256, 0, stream>>>(CFraw, colsum, W2, CFW);
  // conv2 linear (dbuf) -> bf16 h2 [2N,392] with fused x1-add
  gemm_mfma<1><<<dim3(157,7), 256, 0, stream>>>(hh, hl, b2h, b2l, MPAD, NPAD2, nullptr, NNODES, NB2, cmax, CFW, h2);
  // conv2 attention
  a2_kernel<<<1250, 256, 0, stream>>>(h2, atts2, attd2, as2, ad2);
  exp2_kernel<<<2500, 256, 0, stream>>>(csr, dstid, as2, ad2, p2);
  agg2_kernel<<<10000, 256, 0, stream>>>(h2, p2, as2, ad2, rp, csr, b2, out);
}

// Round 10
// 596.002 us; speedup vs baseline: 1.1627x; 1.1225x over previous
//
#include <hip/hip_runtime.h>

#define NNODES 20000
#define MPAD   20096    // NNODES padded to multiple of 128
#define NEDGES 320000
#define FIN    512
#define HC1    512      // H1*HID
#define NHEAD  8
#define OUT2   49
#define NCOL2  392      // NHEAD*OUT2
#define NB2    784      // 2*NCOL2
#define NPAD2  896      // NB2 padded to multiple of 128
#define NCLU   64
#define NIDX   10000
#define NEG    0.2f

typedef unsigned short u16;
typedef short bf16x8 __attribute__((ext_vector_type(8)));
typedef float f32x4 __attribute__((ext_vector_type(4)));

static __device__ __forceinline__ float lrelu(float v){ return v > 0.f ? v : NEG*v; }

// exact split (truncation): f = hi + rem
static __device__ __forceinline__ u16 f2bf_hi(float f, float& rem) {
  union { float f; unsigned u; } c; c.f = f;
  unsigned hb = c.u & 0xFFFF0000u;
  union { unsigned u; float f; } d; d.u = hb;
  rem = f - d.f;
  return (u16)(hb >> 16);
}
static __device__ __forceinline__ u16 f2bf(float f) {   // truncate
  union { float f; unsigned u; } c; c.f = f;
  return (u16)(c.u >> 16);
}
static __device__ __forceinline__ u16 f2bf_rn(float f) { // round-nearest-even
  union { float f; unsigned u; } c; c.f = f;
  unsigned r = c.u + 0x7FFFu + ((c.u >> 16) & 1u);
  return (u16)(r >> 16);
}
static __device__ __forceinline__ float bf2f(u16 u) {
  union { unsigned u; float f; } c; c.u = ((unsigned)u) << 16;
  return c.f;
}
static __device__ __forceinline__ void load8bf(const u16* p, float* o) {
  ushort4 a = *(const ushort4*)p;
  ushort4 b = *(const ushort4*)(p + 4);
  o[0]=bf2f(a.x); o[1]=bf2f(a.y); o[2]=bf2f(a.z); o[3]=bf2f(a.w);
  o[4]=bf2f(b.x); o[5]=bf2f(b.y); o[6]=bf2f(b.z); o[7]=bf2f(b.w);
}

// async 16B global->LDS
typedef __attribute__((address_space(3))) unsigned int lds_u32;
typedef __attribute__((address_space(1))) const unsigned int glb_u32;
static __device__ __forceinline__ void gl_lds16(const u16* g, u16* l) {
  __builtin_amdgcn_global_load_lds((glb_u32*)g, (lds_u32*)l, 16, 0, 0);
}

// ---------------- round x -> packed bf16 [kc][row][8], coalesced both sides via LDS ----------------
__global__ __launch_bounds__(256) void split4_kernel(const float* __restrict__ x,
                                                     u16* __restrict__ xb) {
  __shared__ __align__(16) u16 tb[4][512];
  int wv = threadIdx.x >> 6;
  int lane = threadIdx.x & 63;
  int i = blockIdx.x*4 + wv;
  const float* p = x + (size_t)i*FIN + lane*8;
  float4 v0 = *(const float4*)p, v1 = *(const float4*)(p+4);
  ushort4 h0, h1;
  h0.x = f2bf_rn(v0.x); h0.y = f2bf_rn(v0.y); h0.z = f2bf_rn(v0.z); h0.w = f2bf_rn(v0.w);
  h1.x = f2bf_rn(v1.x); h1.y = f2bf_rn(v1.y); h1.z = f2bf_rn(v1.z); h1.w = f2bf_rn(v1.w);
  *(ushort4*)&tb[wv][lane*8]   = h0; *(ushort4*)&tb[wv][lane*8+4] = h1;
  __syncthreads();
  int kc = threadIdx.x >> 2, nd = threadIdx.x & 3;
  size_t o = ((size_t)kc*MPAD + blockIdx.x*4 + nd)*8;
  *(uint4*)&xb[o] = *(const uint4*)&tb[nd][kc*8];
}

__global__ void tw1_kernel(const float* __restrict__ W1, u16* __restrict__ Th, u16* __restrict__ Tl) {
  int tid = blockIdx.x*256 + threadIdx.x;   // < 64*512
  int kc = tid >> 9, j = tid & 511;
  float rem; ushort4 h0,h1,l0,l1;
  h0.x = f2bf_hi(W1[(size_t)(kc*8+0)*512 + j], rem); l0.x = f2bf(rem);
  h0.y = f2bf_hi(W1[(size_t)(kc*8+1)*512 + j], rem); l0.y = f2bf(rem);
  h0.z = f2bf_hi(W1[(size_t)(kc*8+2)*512 + j], rem); l0.z = f2bf(rem);
  h0.w = f2bf_hi(W1[(size_t)(kc*8+3)*512 + j], rem); l0.w = f2bf(rem);
  h1.x = f2bf_hi(W1[(size_t)(kc*8+4)*512 + j], rem); l1.x = f2bf(rem);
  h1.y = f2bf_hi(W1[(size_t)(kc*8+5)*512 + j], rem); l1.y = f2bf(rem);
  h1.z = f2bf_hi(W1[(size_t)(kc*8+6)*512 + j], rem); l1.z = f2bf(rem);
  h1.w = f2bf_hi(W1[(size_t)(kc*8+7)*512 + j], rem); l1.w = f2bf(rem);
  size_t o = ((size_t)kc*512 + j)*8;
  *(ushort4*)&Th[o] = h0; *(ushort4*)&Th[o+4] = h1;
  *(ushort4*)&Tl[o] = l0; *(ushort4*)&Tl[o+4] = l1;
}

__global__ void tb2_kernel(const float* __restrict__ W2, u16* __restrict__ Th, u16* __restrict__ Tl) {
  int tid = blockIdx.x*256 + threadIdx.x;   // < 64*896
  int kc = tid / NPAD2, j = tid - kc*NPAD2;
  float v[8];
  #pragma unroll
  for (int e = 0; e < 8; e++) {
    int k = kc*8 + e;
    v[e] = (j < NCOL2) ? W2[(size_t)k*NCOL2 + j]
         : ((j < NB2) ? W2[(size_t)(512+k)*NCOL2 + (j - NCOL2)] : 0.f);
  }
  float rem; ushort4 h0,h1,l0,l1;
  h0.x = f2bf_hi(v[0], rem); l0.x = f2bf(rem);
  h0.y = f2bf_hi(v[1], rem); l0.y = f2bf(rem);
  h0.z = f2bf_hi(v[2], rem); l0.z = f2bf(rem);
  h0.w = f2bf_hi(v[3], rem); l0.w = f2bf(rem);
  h1.x = f2bf_hi(v[4], rem); l1.x = f2bf(rem);
  h1.y = f2bf_hi(v[5], rem); l1.y = f2bf(rem);
  h1.z = f2bf_hi(v[6], rem); l1.z = f2bf(rem);
  h1.w = f2bf_hi(v[7], rem); l1.w = f2bf(rem);
  size_t o = ((size_t)kc*NPAD2 + j)*8;
  *(ushort4*)&Th[o] = h0; *(ushort4*)&Th[o+4] = h1;
  *(ushort4*)&Tl[o] = l0; *(ushort4*)&Tl[o+4] = l1;
}

// ---------------- MFMA GEMM: C ~= A(bf16-rn) x (Bh + Bl), dbuf async staging ----------------
// Streams per buffer (u16 idx): A@0 (4 chunks x 1024), Bh@4096, Bl@8192 -> 24KB/buf, 48KB total.
template<int EPI>
__global__ __launch_bounds__(256) void gemm_mfma(
    const u16* __restrict__ A,
    const u16* __restrict__ Bh, const u16* __restrict__ Bl,
    int Apitch, int Bpitch,
    u16* __restrict__ Cbf, int M, int Ncols,
    const int* __restrict__ cmax, const float* __restrict__ CFW, u16* __restrict__ h2)
{
  __shared__ __align__(16) u16 S[2][12288];   // 48 KB
  int tid = threadIdx.x;
  int lane = tid & 63;
  int w = tid >> 6;
  int row0 = blockIdx.x * 128;
  int col0 = blockIdx.y * 128;

  // staging assignment: w0/w1 -> A rows (w*64), w2 -> Bh, w3 -> Bl
  const u16* G; size_t pitch; int sb;
  if (w < 2)       { G = A  + ((size_t)row0 + w*64 + lane)*8; pitch = (size_t)Apitch; sb = w*512; }
  else if (w == 2) { G = Bh + ((size_t)col0 + lane)*8;        pitch = (size_t)Bpitch; sb = 4096; }
  else             { G = Bl + ((size_t)col0 + lane)*8;        pitch = (size_t)Bpitch; sb = 8192; }

  int wr = (w >> 1) * 64;
  int wc = (w & 1) * 64;
  int l16 = lane & 15;
  int q = lane >> 4;

  f32x4 acc[4][4];
  #pragma unroll
  for (int i = 0; i < 4; i++)
    #pragma unroll
    for (int j = 0; j < 4; j++)
      acc[i][j] = (f32x4){0.f, 0.f, 0.f, 0.f};

  // prologue: tile 0 -> S[0]
  if (w < 2) {
    #pragma unroll
    for (int c = 0; c < 4; c++)
      gl_lds16(G + ((size_t)c)*pitch*8, &S[0][c*1024 + sb]);
  } else {
    #pragma unroll
    for (int c = 0; c < 4; c++) {
      gl_lds16(G + ((size_t)c)*pitch*8,       &S[0][sb + c*1024]);
      gl_lds16(G + ((size_t)c)*pitch*8 + 512, &S[0][sb + c*1024 + 512]);
    }
  }

  for (int t = 0; t < 16; t++) {
    int cur = t & 1;
    __syncthreads();
    if (t < 15) {
      if (w < 2) {
        #pragma unroll
        for (int c = 0; c < 4; c++)
          gl_lds16(G + ((size_t)((t+1)*4 + c))*pitch*8, &S[1-cur][c*1024 + sb]);
      } else {
        #pragma unroll
        for (int c = 0; c < 4; c++) {
          gl_lds16(G + ((size_t)((t+1)*4 + c))*pitch*8,       &S[1-cur][sb + c*1024]);
          gl_lds16(G + ((size_t)((t+1)*4 + c))*pitch*8 + 512, &S[1-cur][sb + c*1024 + 512]);
        }
      }
    }
    const u16* P = S[cur];
    bf16x8 a[4], bh[4], bl[4];
    #pragma unroll
    for (int i = 0; i < 4; i++) {
      int ra = q*1024 + (wr + i*16 + l16)*8;
      int rb = q*1024 + (wc + i*16 + l16)*8;
      a[i]  = *(const bf16x8*)&P[ra];
      bh[i] = *(const bf16x8*)&P[4096 + rb];
      bl[i] = *(const bf16x8*)&P[8192 + rb];
    }
    #pragma unroll
    for (int i = 0; i < 4; i++)
      #pragma unroll
      for (int j = 0; j < 4; j++)
        acc[i][j] = __builtin_amdgcn_mfma_f32_16x16x32_bf16(a[i], bh[j], acc[i][j], 0, 0, 0);
    #pragma unroll
    for (int i = 0; i < 4; i++)
      #pragma unroll
      for (int j = 0; j < 4; j++)
        acc[i][j] = __builtin_amdgcn_mfma_f32_16x16x32_bf16(a[i], bl[j], acc[i][j], 0, 0, 0);
  }

  if (EPI == 0) {
    #pragma unroll
    for (int i = 0; i < 4; i++) {
      #pragma unroll
      for (int r = 0; r < 4; r++) {
        int m = row0 + wr + i*16 + q*4 + r;
        if (m < M) {
          #pragma unroll
          for (int j = 0; j < 4; j++)
            Cbf[(size_t)m*Ncols + col0 + wc + j*16 + l16] = f2bf_rn(acc[i][j][r]);
        }
      }
    }
  } else {
    #pragma unroll
    for (int i = 0; i < 4; i++) {
      #pragma unroll
      for (int r = 0; r < 4; r++) {
        int m = row0 + wr + i*16 + q*4 + r;
        if (m >= M) continue;
        int c = cmax[m];
        const float* cf = CFW + (size_t)c * NB2;
        #pragma unroll
        for (int j = 0; j < 4; j++) {
          int n = col0 + wc + j*16 + l16;
          if (n >= NB2) continue;
          float v = acc[i][j][r];
          if (n < NCOL2) h2[(size_t)m*NCOL2 + n] = f2bf_rn(v + cf[NCOL2 + n]);
          else           h2[(size_t)(NNODES + m)*NCOL2 + (n - NCOL2)] = f2bf_rn(v + cf[n - NCOL2]);
        }
      }
    }
  }
}

// ---------------- CSR build ----------------
__global__ void hist_kernel(const int* __restrict__ ei, int* __restrict__ counts) {
  int e = blockIdx.x*256 + threadIdx.x;
  if (e < NEDGES) atomicAdd(&counts[ei[NEDGES + e]], 1);
}

__global__ __launch_bounds__(1024) void scan_kernel(const int* __restrict__ counts,
                                                    int* __restrict__ rowptr, int* __restrict__ cursor) {
  __shared__ int part[1024];
  int t = threadIdx.x;
  const int CH = 20;
  int start = t*CH;
  int end = min(start+CH, NNODES);
  int sum = 0;
  for (int i = start; i < end; i++) sum += counts[i];
  part[t] = sum;
  __syncthreads();
  for (int off = 1; off < 1024; off <<= 1) {
    int v = part[t];
    int add = (t >= off) ? part[t-off] : 0;
    __syncthreads();
    part[t] = v + add;
    __syncthreads();
  }
  int run = part[t] - sum;
  for (int i = start; i < end; i++) {
    rowptr[i] = run; cursor[i] = run;
    run += counts[i];
  }
  if (t == 1023) rowptr[NNODES] = part[1023];
}

__global__ void scatter_kernel(const int* __restrict__ ei, int* __restrict__ cursor,
                               int* __restrict__ csr, int* __restrict__ dstid) {
  int e = blockIdx.x*256 + threadIdx.x;
  if (e < NEDGES) {
    int src = ei[e];
    int dst = ei[NEDGES + e];
    int pos = atomicAdd(&cursor[dst], 1);
    csr[pos] = src;
    dstid[pos] = dst;
  }
}

// ---------------- conv1 attention logits (bf16 hpre row-major) ----------------
__global__ __launch_bounds__(256) void a1_kernel(
    const u16* __restrict__ hpre, const float* __restrict__ atts, const float* __restrict__ attd,
    float* __restrict__ as1, float* __restrict__ ad1)
{
  int lane = threadIdx.x & 63;
  int i = blockIdx.x*4 + (threadIdx.x >> 6);
  float hv[8];
  load8bf(hpre + (size_t)i*HC1 + lane*8, hv);
  const float* ap = atts + lane*8; const float* dp = attd + lane*8;
  float ps = 0.f, pd = 0.f;
  #pragma unroll
  for (int k = 0; k < 8; k++) { ps = fmaf(hv[k], ap[k], ps); pd = fmaf(hv[k], dp[k], pd); }
  ps += __shfl_down(ps, 4, 8); ps += __shfl_down(ps, 2, 8); ps += __shfl_down(ps, 1, 8);
  pd += __shfl_down(pd, 4, 8); pd += __shfl_down(pd, 2, 8); pd += __shfl_down(pd, 1, 8);
  if ((lane & 7) == 0) {
    as1[i*8 + (lane >> 3)] = ps;
    ad1[i*8 + (lane >> 3)] = pd;
  }
}

// ---------------- edge-parallel exp kernels (denominator folded into agg) ----------------
__global__ void exp1_kernel(const int* __restrict__ csr, const int* __restrict__ dstid,
                            const float* __restrict__ as1, const float* __restrict__ ad1,
                            float* __restrict__ p1)
{
  int pos = blockIdx.x*256 + threadIdx.x;   // grid exact: E
  int src = csr[pos], dst = dstid[pos];
  const float* a = as1 + (size_t)src*8;
  const float* d = ad1 + (size_t)dst*8;
  float4 a0 = *(const float4*)a, a1v = *(const float4*)(a+4);
  float4 d0 = *(const float4*)d, d1v = *(const float4*)(d+4);
  float4 o0, o1;
  o0.x = __expf(lrelu(a0.x + d0.x));  o0.y = __expf(lrelu(a0.y + d0.y));
  o0.z = __expf(lrelu(a0.z + d0.z));  o0.w = __expf(lrelu(a0.w + d0.w));
  o1.x = __expf(lrelu(a1v.x + d1v.x)); o1.y = __expf(lrelu(a1v.y + d1v.y));
  o1.z = __expf(lrelu(a1v.z + d1v.z)); o1.w = __expf(lrelu(a1v.w + d1v.w));
  *(float4*)(p1 + (size_t)pos*8)     = o0;
  *(float4*)(p1 + (size_t)pos*8 + 4) = o1;
}

__global__ void exp2_kernel(const int* __restrict__ csr, const int* __restrict__ dstid,
                            const float* __restrict__ as2, const float* __restrict__ ad2,
                            float* __restrict__ p2)
{
  int pos2 = blockIdx.x*256 + threadIdx.x;  // grid exact: 2E
  int half = (pos2 >= NEDGES) ? 1 : 0;
  int pos = pos2 - half*NEDGES;
  int src = csr[pos] + half*NNODES;
  int dst = dstid[pos] + half*NNODES;
  const float* a = as2 + (size_t)src*8;
  const float* d = ad2 + (size_t)dst*8;
  float4 a0 = *(const float4*)a, a1v = *(const float4*)(a+4);
  float4 d0 = *(const float4*)d, d1v = *(const float4*)(d+4);
  float4 o0, o1;
  o0.x = __expf(lrelu(a0.x + d0.x));  o0.y = __expf(lrelu(a0.y + d0.y));
  o0.z = __expf(lrelu(a0.z + d0.z));  o0.w = __expf(lrelu(a0.w + d0.w));
  o1.x = __expf(lrelu(a1v.x + d1v.x)); o1.y = __expf(lrelu(a1v.y + d1v.y));
  o1.z = __expf(lrelu(a1v.z + d1v.z)); o1.w = __expf(lrelu(a1v.w + d1v.w));
  *(float4*)(p2 + (size_t)pos2*8)     = o0;
  *(float4*)(p2 + (size_t)pos2*8 + 4) = o1;
}

// ---------------- conv1 aggregation (s folded) + ELU -> row-major bf16 + packed bf16 ----------------
__global__ __launch_bounds__(256) void agg1_kernel(
    const u16* __restrict__ hpre, const float* __restrict__ p1,
    const float* __restrict__ as1, const float* __restrict__ ad1,
    const int* __restrict__ rowptr, const int* __restrict__ csr, const float* __restrict__ b1,
    u16* __restrict__ hr, u16* __restrict__ hp)
{
  __shared__ __align__(16) u16 sh[4][512];
  int lane = threadIdx.x & 63;
  int wv = threadIdx.x >> 6;
  int i = blockIdx.x*4 + wv;
  int hd = lane >> 3;
  int rs = rowptr[i];
  int deg = rowptr[i+1] - rs;
  float selfp = __expf(lrelu(as1[i*8 + hd] + ad1[i*8 + hd]));
  float acc[8];
  {
    float v[8];
    load8bf(hpre + (size_t)i*HC1 + lane*8, v);
    #pragma unroll
    for (int k = 0; k < 8; k++) acc[k] = selfp * v[k];
  }
  float s = selfp;
  int j = 0;
  for (; j + 1 < deg; j += 2) {
    int s0 = csr[rs+j], s1 = csr[rs+j+1];
    float w0 = p1[(size_t)(rs+j)*8 + hd];
    float w1 = p1[(size_t)(rs+j+1)*8 + hd];
    float v0[8], v1[8];
    load8bf(hpre + (size_t)s0*HC1 + lane*8, v0);
    load8bf(hpre + (size_t)s1*HC1 + lane*8, v1);
    #pragma unroll
    for (int k = 0; k < 8; k++) acc[k] = fmaf(w0, v0[k], acc[k]);
    #pragma unroll
    for (int k = 0; k < 8; k++) acc[k] = fmaf(w1, v1[k], acc[k]);
    s += w0 + w1;
  }
  if (j < deg) {
    int s0 = csr[rs+j];
    float w0 = p1[(size_t)(rs+j)*8 + hd];
    float v0[8];
    load8bf(hpre + (size_t)s0*HC1 + lane*8, v0);
    #pragma unroll
    for (int k = 0; k < 8; k++) acc[k] = fmaf(w0, v0[k], acc[k]);
    s += w0;
  }
  float inv = 1.f / s;
  ushort4 h0, h1;
  {
    float o[8];
    #pragma unroll
    for (int k = 0; k < 8; k++) {
      float v = acc[k]*inv + b1[lane*8 + k];
      o[k] = v > 0.f ? v : __expf(v) - 1.f;   // ELU
    }
    h0.x = f2bf_rn(o[0]); h0.y = f2bf_rn(o[1]); h0.z = f2bf_rn(o[2]); h0.w = f2bf_rn(o[3]);
    h1.x = f2bf_rn(o[4]); h1.y = f2bf_rn(o[5]); h1.z = f2bf_rn(o[6]); h1.w = f2bf_rn(o[7]);
  }
  size_t rb = (size_t)i*HC1 + lane*8;
  *(ushort4*)&hr[rb]   = h0; *(ushort4*)&hr[rb+4] = h1;
  *(ushort4*)&sh[wv][lane*8]   = h0; *(ushort4*)&sh[wv][lane*8+4] = h1;
  __syncthreads();
  int kc = threadIdx.x >> 2, nd = threadIdx.x & 3;
  size_t po = ((size_t)kc*MPAD + blockIdx.x*4 + nd)*8;
  *(uint4*)&hp[po] = *(const uint4*)&sh[nd][kc*8];
}

// ---------------- cluster stage ----------------
__global__ __launch_bounds__(256) void colsum_kernel(
    const float* __restrict__ cluster_id, const int* __restrict__ cidx, float* __restrict__ colsum)
{
  __shared__ float part[4][64];
  int tid = threadIdx.x; int q = tid >> 6, col = tid & 63;
  int start = blockIdx.x*313, end = min(start+313, NIDX);
  float acc = 0.f;
  for (int t = start + q; t < end; t += 4) {
    int node = cidx[t];
    acc += cluster_id[(size_t)node*NCLU + col];
  }
  part[q][col] = acc;
  __syncthreads();
  if (tid < 64) {
    float v = part[0][tid] + part[1][tid] + part[2][tid] + part[3][tid];
    atomicAdd(&colsum[tid], v);
  }
}

// CFraw[c][ch] += cid[node][c]*h[node][ch]; grid (8 ch-slices, 100 t-chunks), 4-way unrolled gather
__global__ __launch_bounds__(256) void cf_kernel(
    const float* __restrict__ cluster_id, const int* __restrict__ cidx,
    const u16* __restrict__ hr, float* __restrict__ CFraw)
{
  int chl = threadIdx.x & 63;
  int cq  = threadIdx.x >> 6;
  int chg = blockIdx.x*64 + chl;
  int start = blockIdx.y*100;               // 100 blocks.y * 100 = NIDX
  float acc[16];
  #pragma unroll
  for (int k = 0; k < 16; k++) acc[k] = 0.f;
  for (int t = start; t < start + 100; t += 4) {
    int4 nd = *(const int4*)(cidx + t);
    u16 h0 = hr[(size_t)nd.x*HC1 + chg], h1 = hr[(size_t)nd.y*HC1 + chg];
    u16 h2v = hr[(size_t)nd.z*HC1 + chg], h3 = hr[(size_t)nd.w*HC1 + chg];
    const float* cp0 = cluster_id + (size_t)nd.x*NCLU + cq*16;
    const float* cp1 = cluster_id + (size_t)nd.y*NCLU + cq*16;
    const float* cp2 = cluster_id + (size_t)nd.z*NCLU + cq*16;
    const float* cp3 = cluster_id + (size_t)nd.w*NCLU + cq*16;
    float hv0 = bf2f(h0), hv1 = bf2f(h1), hv2 = bf2f(h2v), hv3 = bf2f(h3);
    #pragma unroll
    for (int q4 = 0; q4 < 4; q4++) {
      float4 c0 = *(const float4*)(cp0 + q4*4);
      float4 c1 = *(const float4*)(cp1 + q4*4);
      float4 c2 = *(const float4*)(cp2 + q4*4);
      float4 c3 = *(const float4*)(cp3 + q4*4);
      acc[q4*4+0] = fmaf(c0.x, hv0, fmaf(c1.x, hv1, fmaf(c2.x, hv2, fmaf(c3.x, hv3, acc[q4*4+0]))));
      acc[q4*4+1] = fmaf(c0.y, hv0, fmaf(c1.y, hv1, fmaf(c2.y, hv2, fmaf(c3.y, hv3, acc[q4*4+1]))));
      acc[q4*4+2] = fmaf(c0.z, hv0, fmaf(c1.z, hv1, fmaf(c2.z, hv2, fmaf(c3.z, hv3, acc[q4*4+2]))));
      acc[q4*4+3] = fmaf(c0.w, hv0, fmaf(c1.w, hv1, fmaf(c2.w, hv2, fmaf(c3.w, hv3, acc[q4*4+3]))));
    }
  }
  #pragma unroll
  for (int k = 0; k < 16; k++)
    atomicAdd(&CFraw[(size_t)(cq*16 + k)*HC1 + chg], acc[k]);
}

__global__ __launch_bounds__(256) void argmax_kernel(const float* __restrict__ cluster_id, int* __restrict__ cmax)
{
  int lane = threadIdx.x & 63;
  int i = blockIdx.x*4 + (threadIdx.x >> 6);
  float v = cluster_id[(size_t)i*NCLU + lane];
  int idx = lane;
  #pragma unroll
  for (int off = 32; off > 0; off >>= 1) {
    float ov = __shfl_xor(v, off);
    int oi = __shfl_xor(idx, off);
    if (ov > v || (ov == v && oi < idx)) { v = ov; idx = oi; }
  }
  if (lane == 0) cmax[i] = idx;
}

__global__ __launch_bounds__(256) void cfw_kernel(
    const float* __restrict__ CFraw, const float* __restrict__ colsum,
    const float* __restrict__ W2, float* __restrict__ CFW)
{
  int o = blockIdx.x*256 + threadIdx.x;     // < 64*784
  int c = o / NB2, j = o - c*NB2;
  const float* src = (j < NCOL2) ? (W2 + j) : (W2 + (size_t)512*NCOL2 + (j - NCOL2));
  float acc = 0.f;
  for (int k = 0; k < 512; k++) acc = fmaf(CFraw[(size_t)c*512 + k], src[(size_t)k*NCOL2], acc);
  CFW[o] = acc / colsum[c];
}

// ---------------- conv2 attention logits (bf16 h2) ----------------
__global__ __launch_bounds__(256) void a2_kernel(
    const u16* __restrict__ h2, const float* __restrict__ atts, const float* __restrict__ attd,
    float* __restrict__ as2, float* __restrict__ ad2)
{
  __shared__ float rows[32*NCOL2];
  __shared__ float sa[NCOL2], sd[NCOL2];
  int tid = threadIdx.x;
  size_t base = (size_t)blockIdx.x * 32 * NCOL2;
  for (int idx = tid; idx < 32*NCOL2; idx += 256) rows[idx] = bf2f(h2[base + idx]);
  for (int idx = tid; idx < NCOL2; idx += 256) { sa[idx] = atts[idx]; sd[idx] = attd[idx]; }
  __syncthreads();
  int r = tid >> 3, hd = tid & 7;
  const float* rp = rows + r*NCOL2 + hd*OUT2;
  const float* ap = sa + hd*OUT2;
  const float* dp = sd + hd*OUT2;
  float ps = 0.f, pd = 0.f;
  #pragma unroll
  for (int j = 0; j < OUT2; j++) { float v = rp[j]; ps = fmaf(v, ap[j], ps); pd = fmaf(v, dp[j], pd); }
  int node = blockIdx.x*32 + r;
  as2[node*8 + hd] = ps;
  ad2[node*8 + hd] = pd;
}

// ---------------- conv2 aggregation: head-per-lane, s folded, 4-edge unroll ----------------
__global__ __launch_bounds__(256) void agg2_kernel(
    const u16* __restrict__ h2, const float* __restrict__ p2,
    const float* __restrict__ as2, const float* __restrict__ ad2,
    const int* __restrict__ rowptr, const int* __restrict__ csr, const float* __restrict__ b2,
    float* __restrict__ out)
{
  __shared__ float red[4][NCOL2];
  int lane = threadIdx.x & 63;
  int w = threadIdx.x >> 6;
  int u = blockIdx.x*4 + w;
  int bn = (u < NNODES) ? u : u - NNODES;
  int off = u - bn;
  int rs = rowptr[bn];
  int deg = rowptr[bn+1] - rs;
  size_t pbase = (size_t)rs + (off ? NEDGES : 0);
  int hd = lane >> 3, sub = lane & 7;
  int cbase = hd*OUT2 + sub;
  float selfp = __expf(lrelu(as2[u*8 + hd] + ad2[u*8 + hd]));
  float acc[7];
  {
    const u16* own = h2 + (size_t)u*NCOL2 + cbase;
    #pragma unroll
    for (int k = 0; k < 7; k++)
      acc[k] = (sub + 8*k < OUT2) ? selfp * bf2f(own[8*k]) : 0.f;
  }
  float s = selfp;
  int j = 0;
  for (; j + 3 < deg; j += 4) {
    int s0 = csr[rs+j]   + off, s1 = csr[rs+j+1] + off;
    int s2 = csr[rs+j+2] + off, s3 = csr[rs+j+3] + off;
    float w0 = p2[(pbase+j)*8   + hd], w1 = p2[(pbase+j+1)*8 + hd];
    float w2 = p2[(pbase+j+2)*8 + hd], w3 = p2[(pbase+j+3)*8 + hd];
    const u16* r0 = h2 + (size_t)s0*NCOL2 + cbase;
    const u16* r1 = h2 + (size_t)s1*NCOL2 + cbase;
    const u16* r2 = h2 + (size_t)s2*NCOL2 + cbase;
    const u16* r3 = h2 + (size_t)s3*NCOL2 + cbase;
    #pragma unroll
    for (int k = 0; k < 7; k++) {
      if (sub + 8*k < OUT2) {
        acc[k] = fmaf(w0, bf2f(r0[8*k]), acc[k]);
        acc[k] = fmaf(w1, bf2f(r1[8*k]), acc[k]);
        acc[k] = fmaf(w2, bf2f(r2[8*k]), acc[k]);
        acc[k] = fmaf(w3, bf2f(r3[8*k]), acc[k]);
      }
    }
    s += (w0 + w1) + (w2 + w3);
  }
  for (; j < deg; j++) {
    int s0 = csr[rs+j] + off;
    float w0 = p2[(pbase+j)*8 + hd];
    const u16* r0 = h2 + (size_t)s0*NCOL2 + cbase;
    #pragma unroll
    for (int k = 0; k < 7; k++)
      if (sub + 8*k < OUT2) acc[k] = fmaf(w0, bf2f(r0[8*k]), acc[k]);
    s += w0;
  }
  float inv = 1.f / s;
  #pragma unroll
  for (int k = 0; k < 7; k++)
    if (sub + 8*k < OUT2) red[w][cbase + 8*k] = acc[k] * inv;
  __syncthreads();
  if (lane < OUT2) {
    float t = 0.f;
    #pragma unroll
    for (int h = 0; h < 8; h++) t += red[w][h*OUT2 + lane];
    out[(size_t)u*OUT2 + lane] = 0.125f*t + b2[lane];
  }
}

// ---------------- launch ----------------
extern "C" void kernel_launch(void* const* d_in, const int* in_sizes, int n_in,
                              void* d_out, int out_size, void* d_ws, size_t ws_size,
                              hipStream_t stream)
{
  (void)in_sizes; (void)n_in; (void)out_size; (void)ws_size;
  const float* x     = (const float*)d_in[0];
  const int*   ei    = (const int*)d_in[1];
  const float* cid   = (const float*)d_in[2];
  const int*   cidx  = (const int*)d_in[3];
  const float* W1    = (const float*)d_in[4];
  const float* atts1 = (const float*)d_in[5];
  const float* attd1 = (const float*)d_in[6];
  const float* b1    = (const float*)d_in[7];
  const float* W2    = (const float*)d_in[8];
  const float* atts2 = (const float*)d_in[9];
  const float* attd2 = (const float*)d_in[10];
  const float* b2    = (const float*)d_in[11];
  float* out = (float*)d_out;

  char* ws = (char*)d_ws;
  size_t off = 0;
  auto alloc = [&](size_t b){ size_t r = off; off += (b + 255) & ~(size_t)255; return r; };
  size_t o_hpre = alloc((size_t)NNODES*HC1*2);          // bf16 row-major
  size_t o_h2   = alloc((size_t)2*NNODES*NCOL2*2);      // bf16 row-major
  size_t o_xb   = alloc((size_t)64*MPAD*8*2);           // packed chunk-major bf16-rn
  size_t o_hp   = alloc((size_t)64*MPAD*8*2);           // packed h bf16-rn
  size_t o_hr   = alloc((size_t)NNODES*HC1*2);          // row-major h bf16-rn (cf gather)
  size_t o_w1h  = alloc((size_t)64*512*8*2);
  size_t o_w1l  = alloc((size_t)64*512*8*2);
  size_t o_b2h  = alloc((size_t)64*NPAD2*8*2);
  size_t o_b2l  = alloc((size_t)64*NPAD2*8*2);
  size_t o_CFW  = alloc((size_t)NCLU*NB2*4);
  size_t o_as1  = alloc((size_t)NNODES*8*4);
  size_t o_ad1  = alloc((size_t)NNODES*8*4);
  size_t o_as2  = alloc((size_t)2*NNODES*8*4);
  size_t o_ad2  = alloc((size_t)2*NNODES*8*4);
  size_t o_p1   = alloc((size_t)NEDGES*8*4);
  size_t o_p2   = alloc((size_t)2*NEDGES*8*4);
  size_t o_rp   = alloc((size_t)(NNODES+1)*4);
  size_t o_cur  = alloc((size_t)NNODES*4);
  size_t o_csr  = alloc((size_t)NEDGES*4);
  size_t o_dst  = alloc((size_t)NEDGES*4);
  size_t o_cmax = alloc((size_t)NNODES*4);
  size_t o_cnt  = alloc((size_t)NNODES*4);
  size_t o_csum = alloc(256 + (size_t)NCLU*HC1*4);

  u16*   hpre  = (u16*)(ws + o_hpre);
  u16*   h2    = (u16*)(ws + o_h2);
  u16*   xb    = (u16*)(ws + o_xb);
  u16*   hp    = (u16*)(ws + o_hp);
  u16*   hr    = (u16*)(ws + o_hr);
  u16*   w1h   = (u16*)(ws + o_w1h);
  u16*   w1l   = (u16*)(ws + o_w1l);
  u16*   b2h   = (u16*)(ws + o_b2h);
  u16*   b2l   = (u16*)(ws + o_b2l);
  float* CFW   = (float*)(ws + o_CFW);
  float* as1   = (float*)(ws + o_as1);
  float* ad1   = (float*)(ws + o_ad1);
  float* as2   = (float*)(ws + o_as2);
  float* ad2   = (float*)(ws + o_ad2);
  float* p1    = (float*)(ws + o_p1);
  float* p2    = (float*)(ws + o_p2);
  int*   rp    = (int*)(ws + o_rp);
  int*   cur   = (int*)(ws + o_cur);
  int*   csr   = (int*)(ws + o_csr);
  int*   dstid = (int*)(ws + o_dst);
  int*   cmax  = (int*)(ws + o_cmax);
  int*   cnt   = (int*)(ws + o_cnt);
  float* colsum= (float*)(ws + o_csum);
  float* CFraw = (float*)(ws + o_csum + 256);

  hipMemsetAsync(ws + o_cnt, 0, (size_t)NNODES*4, stream);
  hipMemsetAsync(ws + o_csum, 0, 256 + (size_t)NCLU*HC1*4, stream);

  // repack/split inputs
  split4_kernel<<<5000, 256, 0, stream>>>(x, xb);
  tw1_kernel<<<128, 256, 0, stream>>>(W1, w1h, w1l);
  tb2_kernel<<<224, 256, 0, stream>>>(W2, b2h, b2l);
  // CSR (shared by both convs)
  hist_kernel<<<1250, 256, 0, stream>>>(ei, cnt);
  scan_kernel<<<1, 1024, 0, stream>>>(cnt, rp, cur);
  scatter_kernel<<<1250, 256, 0, stream>>>(ei, cur, csr, dstid);
  // conv1 linear: x(bf16) @ (W1h+W1l) -> bf16 hpre
  gemm_mfma<0><<<dim3(157,4), 256, 0, stream>>>(xb, w1h, w1l, MPAD, 512, hpre, NNODES, 512, nullptr, nullptr, nullptr);
  // conv1 attention
  a1_kernel<<<5000, 256, 0, stream>>>(hpre, atts1, attd1, as1, ad1);
  exp1_kernel<<<1250, 256, 0, stream>>>(csr, dstid, as1, ad1, p1);
  agg1_kernel<<<5000, 256, 0, stream>>>(hpre, p1, as1, ad1, rp, csr, b1, hr, hp);
  // cluster features
  colsum_kernel<<<32, 256, 0, stream>>>(cid, cidx, colsum);
  cf_kernel<<<dim3(8,100), 256, 0, stream>>>(cid, cidx, hr, CFraw);
  argmax_kernel<<<5000, 256, 0, stream>>>(cid, cmax);
  cfw_kernel<<<196, 256, 0, stream>>>(CFraw, colsum, W2, CFW);
  // conv2 linear: h(bf16) @ (B2h+B2l) -> bf16 h2 [2N,392] with fused x1-add
  gemm_mfma<1><<<dim3(157,7), 256, 0, stream>>>(hp, b2h, b2l, MPAD, NPAD2, nullptr, NNODES, NB2, cmax, CFW, h2);
  // conv2 attention
  a2_kernel<<<1250, 256, 0, stream>>>(h2, atts2, attd2, as2, ad2);
  exp2_kernel<<<2500, 256, 0, stream>>>(csr, dstid, as2, ad2, p2);
  agg2_kernel<<<10000, 256, 0, stream>>>(h2, p2, as2, ad2, rp, csr, b2, out);
}